// Round 1
// baseline (5393.047 us; speedup 1.0000x reference)
//
#include <hip/hip_runtime.h>
#include <hip/hip_bf16.h>
#include <math.h>

#define NUM_USERS 60000
#define NUM_ITEMS 30000
#define DD 64
#define SEMD 1024
#define HIDD 32
#define KNBR 32
#define NNZE 2000000
#define NLAYERS 3
#define BBATCH 4096
#define LALPHA 0.2f
#define NTOT (NUM_USERS + NUM_ITEMS)

// ---------- K0: wa1[k] = sum_h W_att[k][h]*a1[h], wa2 likewise ----------
__global__ __launch_bounds__(1024) void prep_wa(const float* __restrict__ W_att,
                                                const float* __restrict__ a_att,
                                                float* __restrict__ wa1,
                                                float* __restrict__ wa2) {
    int k = threadIdx.x;  // 0..1023
    float d1 = 0.f, d2 = 0.f;
#pragma unroll
    for (int h = 0; h < HIDD; ++h) {
        float w = W_att[k * HIDD + h];
        d1 += w * a_att[h];
        d2 += w * a_att[HIDD + h];
    }
    wa1[k] = d1;
    wa2[k] = d2;
}

// ---------- tiled GEMM + bias + ELU + merge: out = (emb + elu(A@W + b))*0.5 ----------
// A:[M,1024], W:[1024,64]. BM=64, BK=32, 256 threads, 4x4 microtile.
__global__ __launch_bounds__(256) void gemm_merge(
    const float* __restrict__ A,
    const float* __restrict__ W,
    const float* __restrict__ bias,
    const float* __restrict__ emb,
    float* __restrict__ out0,
    float* __restrict__ out1,   // optional second destination (may be null)
    int M) {
    __shared__ float Al[32][68];  // [k][row], padded (272B row: 16B aligned, bank-rotated)
    __shared__ float Wl[32][68];  // [k][col]

    int tid = threadIdx.x;
    int row0 = blockIdx.x * 64;
    int tx = tid & 15, ty = tid >> 4;

    float acc[4][4] = {};

    int a_row = tid >> 2;        // 0..63
    int a_k = (tid & 3) * 8;     // 0,8,16,24
    int w_k = tid >> 3;          // 0..31
    int w_c = (tid & 7) * 8;     // 0,8,..,56

    for (int k0 = 0; k0 < SEMD; k0 += 32) {
        float4 va0 = make_float4(0.f, 0.f, 0.f, 0.f), va1 = va0;
        if (row0 + a_row < M) {
            const float* src = A + (size_t)(row0 + a_row) * SEMD + k0 + a_k;
            va0 = *(const float4*)src;
            va1 = *(const float4*)(src + 4);
        }
        const float* wsrc = W + (size_t)(k0 + w_k) * DD + w_c;
        float4 vw0 = *(const float4*)wsrc;
        float4 vw1 = *(const float4*)(wsrc + 4);

        __syncthreads();  // previous tile fully consumed
        Al[a_k + 0][a_row] = va0.x; Al[a_k + 1][a_row] = va0.y;
        Al[a_k + 2][a_row] = va0.z; Al[a_k + 3][a_row] = va0.w;
        Al[a_k + 4][a_row] = va1.x; Al[a_k + 5][a_row] = va1.y;
        Al[a_k + 6][a_row] = va1.z; Al[a_k + 7][a_row] = va1.w;
        *(float4*)&Wl[w_k][w_c] = vw0;
        *(float4*)&Wl[w_k][w_c + 4] = vw1;
        __syncthreads();

#pragma unroll
        for (int k = 0; k < 32; ++k) {
            float4 av = *(const float4*)&Al[k][ty * 4];
            float4 bv = *(const float4*)&Wl[k][tx * 4];
            float a4[4] = {av.x, av.y, av.z, av.w};
            float b4[4] = {bv.x, bv.y, bv.z, bv.w};
#pragma unroll
            for (int i = 0; i < 4; ++i)
#pragma unroll
                for (int j = 0; j < 4; ++j) acc[i][j] += a4[i] * b4[j];
        }
    }

#pragma unroll
    for (int i = 0; i < 4; ++i) {
        int row = row0 + ty * 4 + i;
        if (row < M) {
#pragma unroll
            for (int j = 0; j < 4; ++j) {
                int c = tx * 4 + j;
                float x = acc[i][j] + bias[c];
                float e = x > 0.f ? x : (expf(x) - 1.f);
                float v = (emb[(size_t)row * DD + c] + e) * 0.5f;
                out0[(size_t)row * DD + c] = v;
                if (out1) out1[(size_t)row * DD + c] = v;
            }
        }
    }
}

// ---------- s1/s2 GEMV: one wave per item row ----------
__global__ __launch_bounds__(256) void s12_kernel(const float* __restrict__ sem,
                                                  const float* __restrict__ wa1,
                                                  const float* __restrict__ wa2,
                                                  float* __restrict__ s1,
                                                  float* __restrict__ s2) {
    int gid = blockIdx.x * 256 + threadIdx.x;
    int row = gid >> 6;
    int lane = gid & 63;
    if (row >= NUM_ITEMS) return;
    const float* a = sem + (size_t)row * SEMD;
    float d1 = 0.f, d2 = 0.f;
#pragma unroll
    for (int it = 0; it < 4; ++it) {
        int base = (it * 64 + lane) * 4;
        float4 v = *(const float4*)(a + base);
        float4 w1 = *(const float4*)(wa1 + base);
        float4 w2 = *(const float4*)(wa2 + base);
        d1 += v.x * w1.x + v.y * w1.y + v.z * w1.z + v.w * w1.w;
        d2 += v.x * w2.x + v.y * w2.y + v.z * w2.z + v.w * w2.w;
    }
#pragma unroll
    for (int m = 32; m; m >>= 1) {
        d1 += __shfl_xor(d1, m);
        d2 += __shfl_xor(d2, m);
    }
    if (lane == 0) {
        s1[row] = d1;
        s2[row] = d2;
    }
}

// ---------- attention + h' + merge: one wave per item row ----------
__global__ __launch_bounds__(256) void att_kernel(const int* __restrict__ adj,
                                                  const float* __restrict__ s1,
                                                  const float* __restrict__ s2,
                                                  const float* __restrict__ M0,
                                                  float* __restrict__ cur,
                                                  float* __restrict__ sum_) {
    int gid = blockIdx.x * 256 + threadIdx.x;
    int row = gid >> 6;
    int lane = gid & 63;
    if (row >= NUM_ITEMS) return;
    int kk = lane & 31;
    int col = adj[(size_t)row * KNBR + kk];
    float e = s1[col] + s2[row];
    e = e > 0.f ? e : LALPHA * e;
    // softmax over the 32-group (duplicated in both wave halves)
    float mx = e;
#pragma unroll
    for (int m = 1; m < 32; m <<= 1) mx = fmaxf(mx, __shfl_xor(mx, m));
    float ex = expf(e - mx);
    float ssum = ex;
#pragma unroll
    for (int m = 1; m < 32; m <<= 1) ssum += __shfl_xor(ssum, m);
    float w = ex / ssum;
    // h[lane] = sum_k w_k * M0[col_k][lane]
    float h = 0.f;
#pragma unroll 8
    for (int k = 0; k < 32; ++k) {
        float wk = __shfl(w, k);
        int ck = __shfl(col, k);
        h += wk * M0[(size_t)ck * DD + lane];
    }
    float eh = h > 0.f ? h : (expf(h) - 1.f);
    float v = (M0[(size_t)row * DD + lane] + eh) * 0.5f;
    size_t o = (size_t)(NUM_USERS + row) * DD + lane;
    cur[o] = v;
    sum_[o] = v;
}

// ---------- segment-sum layer: edge-parallel atomics ----------
__global__ __launch_bounds__(256) void edge_kernel(const int* __restrict__ rows,
                                                   const int* __restrict__ cols,
                                                   const float* __restrict__ vals,
                                                   const float* __restrict__ cur,
                                                   float* __restrict__ nxt) {
    long long gid = (long long)blockIdx.x * 256 + threadIdx.x;
    int e = (int)(gid >> 4);
    int sub = (int)(gid & 15);
    if (e >= NNZE) return;
    int r = rows[e];
    int c = cols[e];
    float v = vals[e];
    float4 x = *(const float4*)(cur + (size_t)c * DD + sub * 4);
    float* dst = nxt + (size_t)r * DD + sub * 4;
    atomicAdd(dst + 0, v * x.x);
    atomicAdd(dst + 1, v * x.y);
    atomicAdd(dst + 2, v * x.z);
    atomicAdd(dst + 3, v * x.w);
}

// ---------- sum_ += nxt ----------
__global__ __launch_bounds__(256) void add_kernel(float* __restrict__ sum_,
                                                  const float* __restrict__ nxt, int n4) {
    int i = blockIdx.x * 256 + threadIdx.x;
    if (i < n4) {
        float4 s = ((const float4*)sum_)[i];
        float4 a = ((const float4*)nxt)[i];
        s.x += a.x; s.y += a.y; s.z += a.z; s.w += a.w;
        ((float4*)sum_)[i] = s;
    }
}

// ---------- final gather + dot ----------
__global__ __launch_bounds__(256) void gamma_kernel(const int* __restrict__ users,
                                                    const int* __restrict__ items,
                                                    const float* __restrict__ sum_,
                                                    float* __restrict__ out) {
    int gid = blockIdx.x * 256 + threadIdx.x;
    int b = gid >> 6;
    int lane = gid & 63;
    if (b >= BBATCH) return;
    int u = users[b];
    int it = items[b];
    float pu = sum_[(size_t)u * DD + lane];
    float pi = sum_[(size_t)(NUM_USERS + it) * DD + lane];
    float p = pu * pi;
#pragma unroll
    for (int m = 32; m; m >>= 1) p += __shfl_xor(p, m);
    if (lane == 0) out[b] = p * 0.0625f;  // (1/4 mean) * (1/4 mean)
}

extern "C" void kernel_launch(void* const* d_in, const int* in_sizes, int n_in,
                              void* d_out, int out_size, void* d_ws, size_t ws_size,
                              hipStream_t stream) {
    const int* users = (const int*)d_in[0];
    const int* items = (const int*)d_in[1];
    const int* adj = (const int*)d_in[2];
    const int* grows = (const int*)d_in[3];
    const int* gcols = (const int*)d_in[4];
    const float* gvals = (const float*)d_in[5];
    const float* sem = (const float*)d_in[6];
    const float* usem = (const float*)d_in[7];
    const float* emb_user = (const float*)d_in[8];
    const float* emb_item = (const float*)d_in[9];
    const float* W_sem = (const float*)d_in[10];
    const float* b_sem = (const float*)d_in[11];
    const float* W_usem = (const float*)d_in[12];
    const float* b_usem = (const float*)d_in[13];
    const float* W_att = (const float*)d_in[14];
    const float* a_att = (const float*)d_in[15];
    float* out = (float*)d_out;

    float* ws = (float*)d_ws;
    size_t NE = (size_t)NTOT * DD;
    float* sum_ = ws;
    float* bufA = sum_ + NE;
    float* bufB = bufA + NE;
    float* M0 = bufB + NE;
    float* s1 = M0 + (size_t)NUM_ITEMS * DD;
    float* s2 = s1 + NUM_ITEMS;
    float* wa1 = s2 + NUM_ITEMS;
    float* wa2 = wa1 + SEMD;

    prep_wa<<<1, 1024, 0, stream>>>(W_att, a_att, wa1, wa2);
    // users: write merged into bufA(=cur layer0) rows [0,60000) and sum_
    gemm_merge<<<(NUM_USERS + 63) / 64, 256, 0, stream>>>(usem, W_usem, b_usem, emb_user,
                                                          bufA, sum_, NUM_USERS);
    // items: write merged (pre-attention) into M0
    gemm_merge<<<(NUM_ITEMS + 63) / 64, 256, 0, stream>>>(sem, W_sem, b_sem, emb_item,
                                                          M0, nullptr, NUM_ITEMS);
    s12_kernel<<<(NUM_ITEMS * 64 + 255) / 256, 256, 0, stream>>>(sem, wa1, wa2, s1, s2);
    att_kernel<<<(NUM_ITEMS * 64 + 255) / 256, 256, 0, stream>>>(adj, s1, s2, M0, bufA, sum_);

    float* cur = bufA;
    float* nxt = bufB;
    for (int l = 0; l < NLAYERS; ++l) {
        hipMemsetAsync(nxt, 0, NE * sizeof(float), stream);
        edge_kernel<<<(int)(((long long)NNZE * 16 + 255) / 256), 256, 0, stream>>>(grows, gcols,
                                                                                   gvals, cur, nxt);
        add_kernel<<<((int)(NE / 4) + 255) / 256, 256, 0, stream>>>(sum_, nxt, (int)(NE / 4));
        float* t = cur;
        cur = nxt;
        nxt = t;
    }
    gamma_kernel<<<(BBATCH * 64 + 255) / 256, 256, 0, stream>>>(users, items, sum_, out);
}

// Round 2
// 1064.533 us; speedup vs baseline: 5.0661x; 5.0661x over previous
//
#include <hip/hip_runtime.h>
#include <hip/hip_bf16.h>
#include <math.h>

#define NUM_USERS 60000
#define NUM_ITEMS 30000
#define DD 64
#define SEMD 1024
#define HIDD 32
#define KNBR 32
#define NNZE 2000000
#define NLAYERS 3
#define BBATCH 4096
#define LALPHA 0.2f
#define NTOT (NUM_USERS + NUM_ITEMS)

// ---------- K0: wa1[k] = sum_h W_att[k][h]*a1[h], wa2 likewise ----------
__global__ __launch_bounds__(1024) void prep_wa(const float* __restrict__ W_att,
                                                const float* __restrict__ a_att,
                                                float* __restrict__ wa1,
                                                float* __restrict__ wa2) {
    int k = threadIdx.x;  // 0..1023
    float d1 = 0.f, d2 = 0.f;
#pragma unroll
    for (int h = 0; h < HIDD; ++h) {
        float w = W_att[k * HIDD + h];
        d1 += w * a_att[h];
        d2 += w * a_att[HIDD + h];
    }
    wa1[k] = d1;
    wa2[k] = d2;
}

// ---------- tiled GEMM + bias + ELU + merge: out = (emb + elu(A@W + b))*0.5 ----------
__global__ __launch_bounds__(256) void gemm_merge(
    const float* __restrict__ A,
    const float* __restrict__ W,
    const float* __restrict__ bias,
    const float* __restrict__ emb,
    float* __restrict__ out0,
    float* __restrict__ out1,   // optional second destination (may be null)
    int M) {
    __shared__ float Al[32][68];
    __shared__ float Wl[32][68];

    int tid = threadIdx.x;
    int row0 = blockIdx.x * 64;
    int tx = tid & 15, ty = tid >> 4;

    float acc[4][4] = {};

    int a_row = tid >> 2;
    int a_k = (tid & 3) * 8;
    int w_k = tid >> 3;
    int w_c = (tid & 7) * 8;

    for (int k0 = 0; k0 < SEMD; k0 += 32) {
        float4 va0 = make_float4(0.f, 0.f, 0.f, 0.f), va1 = va0;
        if (row0 + a_row < M) {
            const float* src = A + (size_t)(row0 + a_row) * SEMD + k0 + a_k;
            va0 = *(const float4*)src;
            va1 = *(const float4*)(src + 4);
        }
        const float* wsrc = W + (size_t)(k0 + w_k) * DD + w_c;
        float4 vw0 = *(const float4*)wsrc;
        float4 vw1 = *(const float4*)(wsrc + 4);

        __syncthreads();
        Al[a_k + 0][a_row] = va0.x; Al[a_k + 1][a_row] = va0.y;
        Al[a_k + 2][a_row] = va0.z; Al[a_k + 3][a_row] = va0.w;
        Al[a_k + 4][a_row] = va1.x; Al[a_k + 5][a_row] = va1.y;
        Al[a_k + 6][a_row] = va1.z; Al[a_k + 7][a_row] = va1.w;
        *(float4*)&Wl[w_k][w_c] = vw0;
        *(float4*)&Wl[w_k][w_c + 4] = vw1;
        __syncthreads();

#pragma unroll
        for (int k = 0; k < 32; ++k) {
            float4 av = *(const float4*)&Al[k][ty * 4];
            float4 bv = *(const float4*)&Wl[k][tx * 4];
            float a4[4] = {av.x, av.y, av.z, av.w};
            float b4[4] = {bv.x, bv.y, bv.z, bv.w};
#pragma unroll
            for (int i = 0; i < 4; ++i)
#pragma unroll
                for (int j = 0; j < 4; ++j) acc[i][j] += a4[i] * b4[j];
        }
    }

#pragma unroll
    for (int i = 0; i < 4; ++i) {
        int row = row0 + ty * 4 + i;
        if (row < M) {
#pragma unroll
            for (int j = 0; j < 4; ++j) {
                int c = tx * 4 + j;
                float x = acc[i][j] + bias[c];
                float e = x > 0.f ? x : (expf(x) - 1.f);
                float v = (emb[(size_t)row * DD + c] + e) * 0.5f;
                out0[(size_t)row * DD + c] = v;
                if (out1) out1[(size_t)row * DD + c] = v;
            }
        }
    }
}

// ---------- s1/s2 GEMV: one wave per item row ----------
__global__ __launch_bounds__(256) void s12_kernel(const float* __restrict__ sem,
                                                  const float* __restrict__ wa1,
                                                  const float* __restrict__ wa2,
                                                  float* __restrict__ s1,
                                                  float* __restrict__ s2) {
    int gid = blockIdx.x * 256 + threadIdx.x;
    int row = gid >> 6;
    int lane = gid & 63;
    if (row >= NUM_ITEMS) return;
    const float* a = sem + (size_t)row * SEMD;
    float d1 = 0.f, d2 = 0.f;
#pragma unroll
    for (int it = 0; it < 4; ++it) {
        int base = (it * 64 + lane) * 4;
        float4 v = *(const float4*)(a + base);
        float4 w1 = *(const float4*)(wa1 + base);
        float4 w2 = *(const float4*)(wa2 + base);
        d1 += v.x * w1.x + v.y * w1.y + v.z * w1.z + v.w * w1.w;
        d2 += v.x * w2.x + v.y * w2.y + v.z * w2.z + v.w * w2.w;
    }
#pragma unroll
    for (int m = 32; m; m >>= 1) {
        d1 += __shfl_xor(d1, m);
        d2 += __shfl_xor(d2, m);
    }
    if (lane == 0) {
        s1[row] = d1;
        s2[row] = d2;
    }
}

// ---------- attention + h' + merge: one wave per item row ----------
__global__ __launch_bounds__(256) void att_kernel(const int* __restrict__ adj,
                                                  const float* __restrict__ s1,
                                                  const float* __restrict__ s2,
                                                  const float* __restrict__ M0,
                                                  float* __restrict__ cur,
                                                  float* __restrict__ sum_) {
    int gid = blockIdx.x * 256 + threadIdx.x;
    int row = gid >> 6;
    int lane = gid & 63;
    if (row >= NUM_ITEMS) return;
    int kk = lane & 31;
    int col = adj[(size_t)row * KNBR + kk];
    float e = s1[col] + s2[row];
    e = e > 0.f ? e : LALPHA * e;
    float mx = e;
#pragma unroll
    for (int m = 1; m < 32; m <<= 1) mx = fmaxf(mx, __shfl_xor(mx, m));
    float ex = expf(e - mx);
    float ssum = ex;
#pragma unroll
    for (int m = 1; m < 32; m <<= 1) ssum += __shfl_xor(ssum, m);
    float w = ex / ssum;
    float h = 0.f;
#pragma unroll 8
    for (int k = 0; k < 32; ++k) {
        float wk = __shfl(w, k);
        int ck = __shfl(col, k);
        h += wk * M0[(size_t)ck * DD + lane];
    }
    float eh = h > 0.f ? h : (expf(h) - 1.f);
    float v = (M0[(size_t)row * DD + lane] + eh) * 0.5f;
    size_t o = (size_t)(NUM_USERS + row) * DD + lane;
    cur[o] = v;
    sum_[o] = v;
}

// ---------- CSR build: histogram ----------
__global__ __launch_bounds__(256) void hist_kernel(const int* __restrict__ rows,
                                                   int* __restrict__ cnt) {
    int e = blockIdx.x * 256 + threadIdx.x;
    if (e < NNZE) atomicAdd(&cnt[rows[e]], 1);
}

// ---------- CSR build: single-block scan over NTOT counters ----------
__global__ __launch_bounds__(1024) void scan_kernel(const int* __restrict__ cnt,
                                                    int* __restrict__ rowptr,
                                                    int* __restrict__ cursor) {
    __shared__ int part[1024];
    int t = threadIdx.x;
    const int CH = (NTOT + 1023) / 1024;  // 88
    int base = t * CH;
    int s = 0;
    for (int i = 0; i < CH; ++i) {
        int idx = base + i;
        if (idx < NTOT) s += cnt[idx];
    }
    part[t] = s;
    __syncthreads();
    for (int off = 1; off < 1024; off <<= 1) {
        int v = (t >= off) ? part[t - off] : 0;
        __syncthreads();
        part[t] += v;
        __syncthreads();
    }
    int run = (t == 0) ? 0 : part[t - 1];
    for (int i = 0; i < CH; ++i) {
        int idx = base + i;
        if (idx < NTOT) {
            rowptr[idx] = run;
            cursor[idx] = run;
            run += cnt[idx];
        }
    }
    if (t == 1023) rowptr[NTOT] = part[1023];
}

// ---------- CSR build: scatter edges into row-sorted order ----------
__global__ __launch_bounds__(256) void scatter_kernel(const int* __restrict__ rows,
                                                      const int* __restrict__ cols,
                                                      const float* __restrict__ vals,
                                                      int* __restrict__ cursor,
                                                      int* __restrict__ scol,
                                                      float* __restrict__ sval) {
    int e = blockIdx.x * 256 + threadIdx.x;
    if (e >= NNZE) return;
    int r = rows[e];
    int pos = atomicAdd(&cursor[r], 1);
    scol[pos] = cols[e];
    sval[pos] = vals[e];
}

// ---------- SpMM layer (pull): one wave per row, fused sum_ accumulate ----------
__global__ __launch_bounds__(256) void spmm_kernel(const int* __restrict__ rowptr,
                                                   const int* __restrict__ scol,
                                                   const float* __restrict__ sval,
                                                   const float* __restrict__ cur,
                                                   float* __restrict__ nxt,
                                                   float* __restrict__ sum_) {
    int wid = (blockIdx.x * 256 + threadIdx.x) >> 6;
    int lane = threadIdx.x & 63;
    if (wid >= NTOT) return;
    int start = rowptr[wid];
    int end = rowptr[wid + 1];
    float acc = 0.f;
    for (int e0 = start; e0 < end; e0 += 32) {
        int n = min(32, end - e0);
        int c = 0;
        float v = 0.f;
        int sl = lane & 31;
        if (sl < n) {
            c = scol[e0 + sl];
            v = sval[e0 + sl];
        }
        for (int k = 0; k < n; ++k) {
            int ck = __shfl(c, k);
            float vk = __shfl(v, k);
            acc += vk * cur[(size_t)ck * DD + lane];
        }
    }
    size_t o = (size_t)wid * DD + lane;
    nxt[o] = acc;
    sum_[o] += acc;
}

// ---------- final gather + dot ----------
__global__ __launch_bounds__(256) void gamma_kernel(const int* __restrict__ users,
                                                    const int* __restrict__ items,
                                                    const float* __restrict__ sum_,
                                                    float* __restrict__ out) {
    int gid = blockIdx.x * 256 + threadIdx.x;
    int b = gid >> 6;
    int lane = gid & 63;
    if (b >= BBATCH) return;
    int u = users[b];
    int it = items[b];
    float pu = sum_[(size_t)u * DD + lane];
    float pi = sum_[(size_t)(NUM_USERS + it) * DD + lane];
    float p = pu * pi;
#pragma unroll
    for (int m = 32; m; m >>= 1) p += __shfl_xor(p, m);
    if (lane == 0) out[b] = p * 0.0625f;
}

extern "C" void kernel_launch(void* const* d_in, const int* in_sizes, int n_in,
                              void* d_out, int out_size, void* d_ws, size_t ws_size,
                              hipStream_t stream) {
    const int* users = (const int*)d_in[0];
    const int* items = (const int*)d_in[1];
    const int* adj = (const int*)d_in[2];
    const int* grows = (const int*)d_in[3];
    const int* gcols = (const int*)d_in[4];
    const float* gvals = (const float*)d_in[5];
    const float* sem = (const float*)d_in[6];
    const float* usem = (const float*)d_in[7];
    const float* emb_user = (const float*)d_in[8];
    const float* emb_item = (const float*)d_in[9];
    const float* W_sem = (const float*)d_in[10];
    const float* b_sem = (const float*)d_in[11];
    const float* W_usem = (const float*)d_in[12];
    const float* b_usem = (const float*)d_in[13];
    const float* W_att = (const float*)d_in[14];
    const float* a_att = (const float*)d_in[15];
    float* out = (float*)d_out;

    float* ws = (float*)d_ws;
    size_t NE = (size_t)NTOT * DD;  // 5.76M floats
    float* sum_ = ws;
    float* bufA = sum_ + NE;
    float* bufB = bufA + NE;
    // region shared by M0 (pre-layers) and CSR edge arrays (post-att):
    float* region = bufB + NE;
    float* M0 = region;                       // 1.92M floats, dead after att_kernel
    int* scol = (int*)region;                 // 2M ints   (overwrites M0 after att)
    float* sval = region + NNZE;              // 2M floats
    float* tail = region + 2 * (size_t)NNZE;
    float* s1 = tail;
    float* s2 = s1 + NUM_ITEMS;
    float* wa1 = s2 + NUM_ITEMS;
    float* wa2 = wa1 + SEMD;
    int* cnt = (int*)(wa2 + SEMD);
    int* rowptr = cnt + NTOT;
    int* cursor = rowptr + NTOT + 1;

    prep_wa<<<1, 1024, 0, stream>>>(W_att, a_att, wa1, wa2);
    gemm_merge<<<(NUM_USERS + 63) / 64, 256, 0, stream>>>(usem, W_usem, b_usem, emb_user,
                                                          bufA, sum_, NUM_USERS);
    gemm_merge<<<(NUM_ITEMS + 63) / 64, 256, 0, stream>>>(sem, W_sem, b_sem, emb_item,
                                                          M0, nullptr, NUM_ITEMS);
    s12_kernel<<<(NUM_ITEMS * 64 + 255) / 256, 256, 0, stream>>>(sem, wa1, wa2, s1, s2);
    att_kernel<<<(NUM_ITEMS * 64 + 255) / 256, 256, 0, stream>>>(adj, s1, s2, M0, bufA, sum_);

    // ---- CSR build (M0 is dead now; scol/sval reuse its memory) ----
    hipMemsetAsync(cnt, 0, NTOT * sizeof(int), stream);
    hist_kernel<<<(NNZE + 255) / 256, 256, 0, stream>>>(grows, cnt);
    scan_kernel<<<1, 1024, 0, stream>>>(cnt, rowptr, cursor);
    scatter_kernel<<<(NNZE + 255) / 256, 256, 0, stream>>>(grows, gcols, gvals, cursor,
                                                           scol, sval);

    float* cur = bufA;
    float* nxt = bufB;
    for (int l = 0; l < NLAYERS; ++l) {
        spmm_kernel<<<(NTOT * 64 + 255) / 256, 256, 0, stream>>>(rowptr, scol, sval,
                                                                 cur, nxt, sum_);
        float* t = cur;
        cur = nxt;
        nxt = t;
    }
    gamma_kernel<<<(BBATCH * 64 + 255) / 256, 256, 0, stream>>>(users, items, sum_, out);
}

// Round 3
// 870.189 us; speedup vs baseline: 6.1976x; 1.2233x over previous
//
#include <hip/hip_runtime.h>
#include <hip/hip_bf16.h>
#include <math.h>

#define NUM_USERS 60000
#define NUM_ITEMS 30000
#define DD 64
#define SEMD 1024
#define HIDD 32
#define KNBR 32
#define NNZE 2000000
#define NLAYERS 3
#define BBATCH 4096
#define LALPHA 0.2f
#define NTOT (NUM_USERS + NUM_ITEMS)
#define SCAN_NB ((NTOT + 1023) / 1024)  // 88 blocks, 1024 elements each

// ---------- K0: wa1[k] = sum_h W_att[k][h]*a1[h], wa2 likewise ----------
__global__ __launch_bounds__(1024) void prep_wa(const float* __restrict__ W_att,
                                                const float* __restrict__ a_att,
                                                float* __restrict__ wa1,
                                                float* __restrict__ wa2) {
    int k = threadIdx.x;  // 0..1023
    float d1 = 0.f, d2 = 0.f;
#pragma unroll
    for (int h = 0; h < HIDD; ++h) {
        float w = W_att[k * HIDD + h];
        d1 += w * a_att[h];
        d2 += w * a_att[HIDD + h];
    }
    wa1[k] = d1;
    wa2[k] = d2;
}

// ---------- tiled GEMM + bias + ELU + merge: out = (emb + elu(A@W + b))*0.5 ----------
__global__ __launch_bounds__(256) void gemm_merge(
    const float* __restrict__ A,
    const float* __restrict__ W,
    const float* __restrict__ bias,
    const float* __restrict__ emb,
    float* __restrict__ out0,
    float* __restrict__ out1,   // optional second destination (may be null)
    int M) {
    __shared__ float Al[32][68];
    __shared__ float Wl[32][68];

    int tid = threadIdx.x;
    int row0 = blockIdx.x * 64;
    int tx = tid & 15, ty = tid >> 4;

    float acc[4][4] = {};

    int a_row = tid >> 2;
    int a_k = (tid & 3) * 8;
    int w_k = tid >> 3;
    int w_c = (tid & 7) * 8;

    for (int k0 = 0; k0 < SEMD; k0 += 32) {
        float4 va0 = make_float4(0.f, 0.f, 0.f, 0.f), va1 = va0;
        if (row0 + a_row < M) {
            const float* src = A + (size_t)(row0 + a_row) * SEMD + k0 + a_k;
            va0 = *(const float4*)src;
            va1 = *(const float4*)(src + 4);
        }
        const float* wsrc = W + (size_t)(k0 + w_k) * DD + w_c;
        float4 vw0 = *(const float4*)wsrc;
        float4 vw1 = *(const float4*)(wsrc + 4);

        __syncthreads();
        Al[a_k + 0][a_row] = va0.x; Al[a_k + 1][a_row] = va0.y;
        Al[a_k + 2][a_row] = va0.z; Al[a_k + 3][a_row] = va0.w;
        Al[a_k + 4][a_row] = va1.x; Al[a_k + 5][a_row] = va1.y;
        Al[a_k + 6][a_row] = va1.z; Al[a_k + 7][a_row] = va1.w;
        *(float4*)&Wl[w_k][w_c] = vw0;
        *(float4*)&Wl[w_k][w_c + 4] = vw1;
        __syncthreads();

#pragma unroll
        for (int k = 0; k < 32; ++k) {
            float4 av = *(const float4*)&Al[k][ty * 4];
            float4 bv = *(const float4*)&Wl[k][tx * 4];
            float a4[4] = {av.x, av.y, av.z, av.w};
            float b4[4] = {bv.x, bv.y, bv.z, bv.w};
#pragma unroll
            for (int i = 0; i < 4; ++i)
#pragma unroll
                for (int j = 0; j < 4; ++j) acc[i][j] += a4[i] * b4[j];
        }
    }

#pragma unroll
    for (int i = 0; i < 4; ++i) {
        int row = row0 + ty * 4 + i;
        if (row < M) {
#pragma unroll
            for (int j = 0; j < 4; ++j) {
                int c = tx * 4 + j;
                float x = acc[i][j] + bias[c];
                float e = x > 0.f ? x : (expf(x) - 1.f);
                float v = (emb[(size_t)row * DD + c] + e) * 0.5f;
                out0[(size_t)row * DD + c] = v;
                if (out1) out1[(size_t)row * DD + c] = v;
            }
        }
    }
}

// ---------- s1/s2 GEMV: one wave per item row ----------
__global__ __launch_bounds__(256) void s12_kernel(const float* __restrict__ sem,
                                                  const float* __restrict__ wa1,
                                                  const float* __restrict__ wa2,
                                                  float* __restrict__ s1,
                                                  float* __restrict__ s2) {
    int gid = blockIdx.x * 256 + threadIdx.x;
    int row = gid >> 6;
    int lane = gid & 63;
    if (row >= NUM_ITEMS) return;
    const float* a = sem + (size_t)row * SEMD;
    float d1 = 0.f, d2 = 0.f;
#pragma unroll
    for (int it = 0; it < 4; ++it) {
        int base = (it * 64 + lane) * 4;
        float4 v = *(const float4*)(a + base);
        float4 w1 = *(const float4*)(wa1 + base);
        float4 w2 = *(const float4*)(wa2 + base);
        d1 += v.x * w1.x + v.y * w1.y + v.z * w1.z + v.w * w1.w;
        d2 += v.x * w2.x + v.y * w2.y + v.z * w2.z + v.w * w2.w;
    }
#pragma unroll
    for (int m = 32; m; m >>= 1) {
        d1 += __shfl_xor(d1, m);
        d2 += __shfl_xor(d2, m);
    }
    if (lane == 0) {
        s1[row] = d1;
        s2[row] = d2;
    }
}

// ---------- attention + h' + merge: one wave per item row ----------
__global__ __launch_bounds__(256) void att_kernel(const int* __restrict__ adj,
                                                  const float* __restrict__ s1,
                                                  const float* __restrict__ s2,
                                                  const float* __restrict__ M0,
                                                  float* __restrict__ cur,
                                                  float* __restrict__ sum_) {
    int gid = blockIdx.x * 256 + threadIdx.x;
    int row = gid >> 6;
    int lane = gid & 63;
    if (row >= NUM_ITEMS) return;
    int kk = lane & 31;
    int col = adj[(size_t)row * KNBR + kk];
    float e = s1[col] + s2[row];
    e = e > 0.f ? e : LALPHA * e;
    float mx = e;
#pragma unroll
    for (int m = 1; m < 32; m <<= 1) mx = fmaxf(mx, __shfl_xor(mx, m));
    float ex = expf(e - mx);
    float ssum = ex;
#pragma unroll
    for (int m = 1; m < 32; m <<= 1) ssum += __shfl_xor(ssum, m);
    float w = ex / ssum;
    float h = 0.f;
#pragma unroll 8
    for (int k = 0; k < 32; ++k) {
        float wk = __shfl(w, k);
        int ck = __shfl(col, k);
        h += wk * M0[(size_t)ck * DD + lane];
    }
    float eh = h > 0.f ? h : (expf(h) - 1.f);
    float v = (M0[(size_t)row * DD + lane] + eh) * 0.5f;
    size_t o = (size_t)(NUM_USERS + row) * DD + lane;
    cur[o] = v;
    sum_[o] = v;
}

// ---------- CSR build: histogram ----------
__global__ __launch_bounds__(256) void hist_kernel(const int* __restrict__ rows,
                                                   int* __restrict__ cnt) {
    int e = blockIdx.x * 256 + threadIdx.x;
    if (e < NNZE) atomicAdd(&cnt[rows[e]], 1);
}

// ---------- scan phase 1: per-block (1024-element) sums ----------
__global__ __launch_bounds__(256) void scan_blocksums(const int* __restrict__ cnt,
                                                      int* __restrict__ bsum) {
    __shared__ int ws[4];
    int tid = threadIdx.x;
    int base = blockIdx.x * 1024 + tid * 4;
    int s = 0;
    if (base + 3 < NTOT) {
        int4 v = *(const int4*)(cnt + base);
        s = v.x + v.y + v.z + v.w;
    } else {
        for (int i = 0; i < 4; ++i)
            if (base + i < NTOT) s += cnt[base + i];
    }
#pragma unroll
    for (int m = 32; m; m >>= 1) s += __shfl_xor(s, m);
    if ((tid & 63) == 0) ws[tid >> 6] = s;
    __syncthreads();
    if (tid == 0) bsum[blockIdx.x] = ws[0] + ws[1] + ws[2] + ws[3];
}

// ---------- scan phase 2: exclusive scan of block sums (1 small block) ----------
__global__ __launch_bounds__(128) void scan_bsums(const int* __restrict__ bsum,
                                                  int* __restrict__ boff,
                                                  int* __restrict__ rowptr) {
    __shared__ int sh[128];
    int t = threadIdx.x;
    int v = (t < SCAN_NB) ? bsum[t] : 0;
    sh[t] = v;
    __syncthreads();
    for (int off = 1; off < 128; off <<= 1) {
        int x = (t >= off) ? sh[t - off] : 0;
        __syncthreads();
        sh[t] += x;
        __syncthreads();
    }
    if (t < SCAN_NB) boff[t] = (t == 0) ? 0 : sh[t - 1];
    if (t == 127) rowptr[NTOT] = sh[SCAN_NB - 1];
}

// ---------- scan phase 3: block-local scan + offset, write rowptr & cursor ----------
__global__ __launch_bounds__(256) void scan_write(const int* __restrict__ cnt,
                                                  const int* __restrict__ boff,
                                                  int* __restrict__ rowptr,
                                                  int* __restrict__ cursor) {
    __shared__ int wsum[4];
    int tid = threadIdx.x;
    int lane = tid & 63;
    int wave = tid >> 6;
    int base = blockIdx.x * 1024 + tid * 4;

    int e0 = 0, e1 = 0, e2 = 0, e3 = 0;
    if (base + 3 < NTOT) {
        int4 v = *(const int4*)(cnt + base);
        e0 = v.x; e1 = v.y; e2 = v.z; e3 = v.w;
    } else {
        if (base + 0 < NTOT) e0 = cnt[base + 0];
        if (base + 1 < NTOT) e1 = cnt[base + 1];
        if (base + 2 < NTOT) e2 = cnt[base + 2];
    }
    int tsum = e0 + e1 + e2 + e3;

    // wave inclusive scan of tsum
    int s = tsum;
#pragma unroll
    for (int off = 1; off < 64; off <<= 1) {
        int x = __shfl_up(s, off);
        if (lane >= off) s += x;
    }
    if (lane == 63) wsum[wave] = s;
    __syncthreads();
    int woff = 0;
    if (wave > 0) {
        for (int w = 0; w < 4; ++w)
            if (w < wave) woff += wsum[w];
    }
    __syncthreads();
    int excl = boff[blockIdx.x] + woff + (s - tsum);

    int4 r;
    r.x = excl;
    r.y = excl + e0;
    r.z = excl + e0 + e1;
    r.w = excl + e0 + e1 + e2;
    if (base + 3 < NTOT) {
        *(int4*)(rowptr + base) = r;
        *(int4*)(cursor + base) = r;
    } else {
        if (base + 0 < NTOT) { rowptr[base + 0] = r.x; cursor[base + 0] = r.x; }
        if (base + 1 < NTOT) { rowptr[base + 1] = r.y; cursor[base + 1] = r.y; }
        if (base + 2 < NTOT) { rowptr[base + 2] = r.z; cursor[base + 2] = r.z; }
    }
}

// ---------- CSR build: scatter edges into row-sorted order ----------
__global__ __launch_bounds__(256) void scatter_kernel(const int* __restrict__ rows,
                                                      const int* __restrict__ cols,
                                                      const float* __restrict__ vals,
                                                      int* __restrict__ cursor,
                                                      int* __restrict__ scol,
                                                      float* __restrict__ sval) {
    int e = blockIdx.x * 256 + threadIdx.x;
    if (e >= NNZE) return;
    int r = rows[e];
    int pos = atomicAdd(&cursor[r], 1);
    scol[pos] = cols[e];
    sval[pos] = vals[e];
}

// ---------- SpMM layer (pull): one wave per row, fused sum_ accumulate ----------
__global__ __launch_bounds__(256) void spmm_kernel(const int* __restrict__ rowptr,
                                                   const int* __restrict__ scol,
                                                   const float* __restrict__ sval,
                                                   const float* __restrict__ cur,
                                                   float* __restrict__ nxt,
                                                   float* __restrict__ sum_) {
    int wid = (blockIdx.x * 256 + threadIdx.x) >> 6;
    int lane = threadIdx.x & 63;
    if (wid >= NTOT) return;
    int start = rowptr[wid];
    int end = rowptr[wid + 1];
    float acc = 0.f;
    for (int e0 = start; e0 < end; e0 += 32) {
        int n = min(32, end - e0);
        int c = 0;
        float v = 0.f;
        int sl = lane & 31;
        if (sl < n) {
            c = scol[e0 + sl];
            v = sval[e0 + sl];
        }
        for (int k = 0; k < n; ++k) {
            int ck = __shfl(c, k);
            float vk = __shfl(v, k);
            acc += vk * cur[(size_t)ck * DD + lane];
        }
    }
    size_t o = (size_t)wid * DD + lane;
    nxt[o] = acc;
    sum_[o] += acc;
}

// ---------- final gather + dot ----------
__global__ __launch_bounds__(256) void gamma_kernel(const int* __restrict__ users,
                                                    const int* __restrict__ items,
                                                    const float* __restrict__ sum_,
                                                    float* __restrict__ out) {
    int gid = blockIdx.x * 256 + threadIdx.x;
    int b = gid >> 6;
    int lane = gid & 63;
    if (b >= BBATCH) return;
    int u = users[b];
    int it = items[b];
    float pu = sum_[(size_t)u * DD + lane];
    float pi = sum_[(size_t)(NUM_USERS + it) * DD + lane];
    float p = pu * pi;
#pragma unroll
    for (int m = 32; m; m >>= 1) p += __shfl_xor(p, m);
    if (lane == 0) out[b] = p * 0.0625f;
}

extern "C" void kernel_launch(void* const* d_in, const int* in_sizes, int n_in,
                              void* d_out, int out_size, void* d_ws, size_t ws_size,
                              hipStream_t stream) {
    const int* users = (const int*)d_in[0];
    const int* items = (const int*)d_in[1];
    const int* adj = (const int*)d_in[2];
    const int* grows = (const int*)d_in[3];
    const int* gcols = (const int*)d_in[4];
    const float* gvals = (const float*)d_in[5];
    const float* sem = (const float*)d_in[6];
    const float* usem = (const float*)d_in[7];
    const float* emb_user = (const float*)d_in[8];
    const float* emb_item = (const float*)d_in[9];
    const float* W_sem = (const float*)d_in[10];
    const float* b_sem = (const float*)d_in[11];
    const float* W_usem = (const float*)d_in[12];
    const float* b_usem = (const float*)d_in[13];
    const float* W_att = (const float*)d_in[14];
    const float* a_att = (const float*)d_in[15];
    float* out = (float*)d_out;

    float* ws = (float*)d_ws;
    size_t NE = (size_t)NTOT * DD;  // 5.76M floats
    float* sum_ = ws;
    float* bufA = sum_ + NE;
    float* bufB = bufA + NE;
    // region shared by M0 (pre-layers) and CSR edge arrays (post-att):
    float* region = bufB + NE;
    float* M0 = region;                       // 1.92M floats, dead after att_kernel
    int* scol = (int*)region;                 // 2M ints   (overwrites M0 after att)
    float* sval = region + NNZE;              // 2M floats
    float* tail = region + 2 * (size_t)NNZE;
    float* s1 = tail;
    float* s2 = s1 + NUM_ITEMS;
    float* wa1 = s2 + NUM_ITEMS;
    float* wa2 = wa1 + SEMD;
    int* cnt = (int*)(wa2 + SEMD);            // NTOT, 16B-aligned
    int* rowptr = cnt + NTOT;                 // NTOT+1 (padded to +4)
    int* cursor = rowptr + NTOT + 4;          // NTOT, 16B-aligned
    int* bsum = cursor + NTOT;
    int* boff = bsum + SCAN_NB;

    prep_wa<<<1, 1024, 0, stream>>>(W_att, a_att, wa1, wa2);
    gemm_merge<<<(NUM_USERS + 63) / 64, 256, 0, stream>>>(usem, W_usem, b_usem, emb_user,
                                                          bufA, sum_, NUM_USERS);
    gemm_merge<<<(NUM_ITEMS + 63) / 64, 256, 0, stream>>>(sem, W_sem, b_sem, emb_item,
                                                          M0, nullptr, NUM_ITEMS);
    s12_kernel<<<(NUM_ITEMS * 64 + 255) / 256, 256, 0, stream>>>(sem, wa1, wa2, s1, s2);
    att_kernel<<<(NUM_ITEMS * 64 + 255) / 256, 256, 0, stream>>>(adj, s1, s2, M0, bufA, sum_);

    // ---- CSR build (M0 is dead now; scol/sval reuse its memory) ----
    hipMemsetAsync(cnt, 0, NTOT * sizeof(int), stream);
    hist_kernel<<<(NNZE + 255) / 256, 256, 0, stream>>>(grows, cnt);
    scan_blocksums<<<SCAN_NB, 256, 0, stream>>>(cnt, bsum);
    scan_bsums<<<1, 128, 0, stream>>>(bsum, boff, rowptr);
    scan_write<<<SCAN_NB, 256, 0, stream>>>(cnt, boff, rowptr, cursor);
    scatter_kernel<<<(NNZE + 255) / 256, 256, 0, stream>>>(grows, gcols, gvals, cursor,
                                                           scol, sval);

    float* cur = bufA;
    float* nxt = bufB;
    for (int l = 0; l < NLAYERS; ++l) {
        spmm_kernel<<<(NTOT * 64 + 255) / 256, 256, 0, stream>>>(rowptr, scol, sval,
                                                                 cur, nxt, sum_);
        float* t = cur;
        cur = nxt;
        nxt = t;
    }
    gamma_kernel<<<(BBATCH * 64 + 255) / 256, 256, 0, stream>>>(users, items, sum_, out);
}

// Round 4
// 829.059 us; speedup vs baseline: 6.5050x; 1.0496x over previous
//
#include <hip/hip_runtime.h>
#include <hip/hip_bf16.h>
#include <math.h>

#define NUM_USERS 60000
#define NUM_ITEMS 30000
#define DD 64
#define SEMD 1024
#define HIDD 32
#define KNBR 32
#define NNZE 2000000
#define NLAYERS 3
#define BBATCH 4096
#define LALPHA 0.2f
#define NTOT (NUM_USERS + NUM_ITEMS)
#define SCAN_NB ((NTOT + 1023) / 1024)  // 88

typedef unsigned short ushort_t;
typedef short s16x8 __attribute__((ext_vector_type(8)));
typedef float f32x4 __attribute__((ext_vector_type(4)));

__device__ __forceinline__ ushort_t f2bf(float x) {
    unsigned u = __float_as_uint(x);
    return (ushort_t)((u + 0x7FFFu + ((u >> 16) & 1u)) >> 16);
}
__device__ __forceinline__ float bf2f(ushort_t s) {
    return __uint_as_float(((unsigned)s) << 16);
}

// ---------- wa1/wa2 = W_att @ a1 / a2 ----------
__global__ __launch_bounds__(1024) void prep_wa(const float* __restrict__ W_att,
                                                const float* __restrict__ a_att,
                                                float* __restrict__ wa1,
                                                float* __restrict__ wa2) {
    int k = threadIdx.x;
    float d1 = 0.f, d2 = 0.f;
#pragma unroll
    for (int h = 0; h < HIDD; ++h) {
        float w = W_att[k * HIDD + h];
        d1 += w * a_att[h];
        d2 += w * a_att[HIDD + h];
    }
    wa1[k] = d1;
    wa2[k] = d2;
}

// ---------- split W (fp32 [1024][64]) into transposed bf16 hi/lo [64][1024] ----------
__global__ __launch_bounds__(256) void wsplit(const float* __restrict__ Wu,
                                              const float* __restrict__ Ws,
                                              ushort_t* __restrict__ hiU, ushort_t* __restrict__ loU,
                                              ushort_t* __restrict__ hiS, ushort_t* __restrict__ loS) {
    int id = blockIdx.x * 256 + threadIdx.x;  // 0..131071
    int i = id & 65535;
    int k = i & 1023;   // k fastest -> coalesced WT writes
    int c = i >> 10;
    float x = (id < 65536) ? Wu[(size_t)k * DD + c] : Ws[(size_t)k * DD + c];
    ushort_t h = f2bf(x);
    ushort_t l = f2bf(x - bf2f(h));
    ushort_t* dh = (id < 65536) ? hiU : hiS;
    ushort_t* dl = (id < 65536) ? loU : loS;
    dh[(size_t)c * SEMD + k] = h;
    dl[(size_t)c * SEMD + k] = l;
}

// ---------- MFMA bf16x3 GEMM + bias + ELU + merge (+ optional fused s1/s2) ----------
// A:[M,1024] fp32, WT hi/lo:[64][1024] bf16.  out = (emb + elu(A@W+b))*0.5
// BM=128, BK=64, 256 threads (4 waves), each wave 32 rows x 64 cols.
template <bool DOS12>
__global__ __launch_bounds__(256) void gemm_mfma(
    const float* __restrict__ A,
    const ushort_t* __restrict__ WThi,
    const ushort_t* __restrict__ WTlo,
    const float* __restrict__ bias,
    const float* __restrict__ emb,
    float* __restrict__ out32,
    ushort_t* __restrict__ out16,
    int M,
    const float* __restrict__ wa1,
    const float* __restrict__ wa2,
    float* __restrict__ s1,
    float* __restrict__ s2) {
    __shared__ ushort_t Ah[128 * 64];   // swizzled: byte ^= (row&7)<<4
    __shared__ ushort_t Alo[128 * 64];
    __shared__ ushort_t Wh[64 * 64];
    __shared__ ushort_t Wl[64 * 64];

    const int tid = threadIdx.x;
    const int lane = tid & 63;
    const int w = tid >> 6;
    const int l15 = lane & 15;
    const int l4 = lane >> 4;
    const int row0 = blockIdx.x * 128;

    f32x4 acc[2][4] = {};
    float s1p[8] = {}, s2p[8] = {};

    const int srow = tid >> 4;   // 0..15: row-in-pass
    const int sc = tid & 15;     // chunk (4 floats)

    for (int kt = 0; kt < 16; ++kt) {
        const int k0 = kt * 64;
        float4 va1w, va2w;
        if (DOS12) {
            va1w = *(const float4*)(wa1 + k0 + sc * 4);
            va2w = *(const float4*)(wa2 + k0 + sc * 4);
        }
        __syncthreads();  // previous tile consumed
        // ---- stage A (128 rows x 64 k) as bf16 hi/lo ----
#pragma unroll
        for (int p = 0; p < 8; ++p) {
            int rin = p * 16 + srow;
            int grow = row0 + rin;
            float4 v = make_float4(0.f, 0.f, 0.f, 0.f);
            if (grow < M) v = *(const float4*)(A + (size_t)grow * SEMD + k0 + sc * 4);
            if (DOS12) {
                s1p[p] += v.x * va1w.x + v.y * va1w.y + v.z * va1w.z + v.w * va1w.w;
                s2p[p] += v.x * va2w.x + v.y * va2w.y + v.z * va2w.z + v.w * va2w.w;
            }
            ushort4 hv, lv;
            hv.x = f2bf(v.x); lv.x = f2bf(v.x - bf2f(hv.x));
            hv.y = f2bf(v.y); lv.y = f2bf(v.y - bf2f(hv.y));
            hv.z = f2bf(v.z); lv.z = f2bf(v.z - bf2f(hv.z));
            hv.w = f2bf(v.w); lv.w = f2bf(v.w - bf2f(hv.w));
            int boff = rin * 128 + ((sc * 8) ^ ((rin & 7) << 4));
            *(ushort4*)((char*)Ah + boff) = hv;
            *(ushort4*)((char*)Alo + boff) = lv;
        }
        // ---- stage W^T tile (64 cols x 64 k) ----
        {
            int col = tid >> 2, q = tid & 3;
            const ushort_t* sh = WThi + (size_t)col * SEMD + k0 + q * 16;
            const ushort_t* sl = WTlo + (size_t)col * SEMD + k0 + q * 16;
            s16x8 h0 = *(const s16x8*)sh;
            s16x8 h1 = *(const s16x8*)(sh + 8);
            s16x8 l0 = *(const s16x8*)sl;
            s16x8 l1 = *(const s16x8*)(sl + 8);
            char* dh = (char*)Wh + col * 128;
            char* dl = (char*)Wl + col * 128;
            int sw = (col & 7) << 4;
            *(s16x8*)(dh + ((q * 32) ^ sw)) = h0;
            *(s16x8*)(dh + ((q * 32 + 16) ^ sw)) = h1;
            *(s16x8*)(dl + ((q * 32) ^ sw)) = l0;
            *(s16x8*)(dl + ((q * 32 + 16) ^ sw)) = l1;
        }
        __syncthreads();

        // ---- A fragments: rows w*32 + rf*16 + l15, k = kf*32 + l4*8 + j ----
        s16x8 fah[2][2], fal[2][2];
#pragma unroll
        for (int rf = 0; rf < 2; ++rf)
#pragma unroll
            for (int kf = 0; kf < 2; ++kf) {
                int row = w * 32 + rf * 16 + l15;
                int bc = kf * 64 + l4 * 16;
                int off = row * 128 + (bc ^ ((row & 7) << 4));
                fah[rf][kf] = *(const s16x8*)((const char*)Ah + off);
                fal[rf][kf] = *(const s16x8*)((const char*)Alo + off);
            }
#pragma unroll
        for (int cg = 0; cg < 4; ++cg) {
            s16x8 fwh[2], fwl[2];
#pragma unroll
            for (int kf = 0; kf < 2; ++kf) {
                int col = cg * 16 + l15;
                int bc = kf * 64 + l4 * 16;
                int off = col * 128 + (bc ^ ((col & 7) << 4));
                fwh[kf] = *(const s16x8*)((const char*)Wh + off);
                fwl[kf] = *(const s16x8*)((const char*)Wl + off);
            }
#pragma unroll
            for (int rf = 0; rf < 2; ++rf)
#pragma unroll
                for (int kf = 0; kf < 2; ++kf) {
                    acc[rf][cg] = __builtin_amdgcn_mfma_f32_16x16x32_bf16(
                        fah[rf][kf], fwh[kf], acc[rf][cg], 0, 0, 0);
                    acc[rf][cg] = __builtin_amdgcn_mfma_f32_16x16x32_bf16(
                        fah[rf][kf], fwl[kf], acc[rf][cg], 0, 0, 0);
                    acc[rf][cg] = __builtin_amdgcn_mfma_f32_16x16x32_bf16(
                        fal[rf][kf], fwh[kf], acc[rf][cg], 0, 0, 0);
                }
        }
    }

    // ---- fused s1/s2 reduce (16 threads per row share one row's partials) ----
    if (DOS12) {
#pragma unroll
        for (int p = 0; p < 8; ++p) {
            float v1 = s1p[p], v2 = s2p[p];
#pragma unroll
            for (int m = 1; m < 16; m <<= 1) {
                v1 += __shfl_xor(v1, m);
                v2 += __shfl_xor(v2, m);
            }
            int grow = row0 + p * 16 + srow;
            if (sc == 0 && grow < M) {
                s1[grow] = v1;
                s2[grow] = v2;
            }
        }
    }

    // ---- epilogue: D col=lane&15, row=(lane>>4)*4+j ----
#pragma unroll
    for (int rf = 0; rf < 2; ++rf)
#pragma unroll
        for (int cg = 0; cg < 4; ++cg) {
            int col = cg * 16 + l15;
            float b = bias[col];
#pragma unroll
            for (int j = 0; j < 4; ++j) {
                int grow = row0 + w * 32 + rf * 16 + l4 * 4 + j;
                if (grow < M) {
                    float x = acc[rf][cg][j] + b;
                    float e = x > 0.f ? x : (expf(x) - 1.f);
                    float v = (emb[(size_t)grow * DD + col] + e) * 0.5f;
                    out32[(size_t)grow * DD + col] = v;
                    out16[(size_t)grow * DD + col] = f2bf(v);
                }
            }
        }
}

// ---------- attention + h' + merge: one wave per item row ----------
__global__ __launch_bounds__(256) void att_kernel(const int* __restrict__ adj,
                                                  const float* __restrict__ s1,
                                                  const float* __restrict__ s2,
                                                  const float* __restrict__ M0,
                                                  const ushort_t* __restrict__ M0h,
                                                  ushort_t* __restrict__ cur16,
                                                  float* __restrict__ sum_) {
    int gid = blockIdx.x * 256 + threadIdx.x;
    int row = gid >> 6;
    int lane = gid & 63;
    if (row >= NUM_ITEMS) return;
    int kk = lane & 31;
    int col = adj[(size_t)row * KNBR + kk];
    float e = s1[col] + s2[row];
    e = e > 0.f ? e : LALPHA * e;
    float mx = e;
#pragma unroll
    for (int m = 1; m < 32; m <<= 1) mx = fmaxf(mx, __shfl_xor(mx, m));
    float ex = expf(e - mx);
    float ssum = ex;
#pragma unroll
    for (int m = 1; m < 32; m <<= 1) ssum += __shfl_xor(ssum, m);
    float wgt = ex / ssum;
    float h = 0.f;
#pragma unroll 8
    for (int k = 0; k < 32; ++k) {
        float wk = __shfl(wgt, k);
        int ck = __shfl(col, k);
        h += wk * bf2f(M0h[(size_t)ck * DD + lane]);
    }
    float eh = h > 0.f ? h : (expf(h) - 1.f);
    float v = (M0[(size_t)row * DD + lane] + eh) * 0.5f;
    size_t o = (size_t)(NUM_USERS + row) * DD + lane;
    cur16[o] = f2bf(v);
    sum_[o] = v;
}

// ---------- CSR build ----------
__global__ __launch_bounds__(256) void hist_kernel(const int* __restrict__ rows,
                                                   int* __restrict__ cnt) {
    int e = blockIdx.x * 256 + threadIdx.x;
    if (e < NNZE) atomicAdd(&cnt[rows[e]], 1);
}

__global__ __launch_bounds__(256) void scan_blocksums(const int* __restrict__ cnt,
                                                      int* __restrict__ bsum) {
    __shared__ int ws[4];
    int tid = threadIdx.x;
    int base = blockIdx.x * 1024 + tid * 4;
    int s = 0;
    if (base + 3 < NTOT) {
        int4 v = *(const int4*)(cnt + base);
        s = v.x + v.y + v.z + v.w;
    } else {
        for (int i = 0; i < 4; ++i)
            if (base + i < NTOT) s += cnt[base + i];
    }
#pragma unroll
    for (int m = 32; m; m >>= 1) s += __shfl_xor(s, m);
    if ((tid & 63) == 0) ws[tid >> 6] = s;
    __syncthreads();
    if (tid == 0) bsum[blockIdx.x] = ws[0] + ws[1] + ws[2] + ws[3];
}

__global__ __launch_bounds__(128) void scan_bsums(const int* __restrict__ bsum,
                                                  int* __restrict__ boff,
                                                  int* __restrict__ rowptr) {
    __shared__ int sh[128];
    int t = threadIdx.x;
    int v = (t < SCAN_NB) ? bsum[t] : 0;
    sh[t] = v;
    __syncthreads();
    for (int off = 1; off < 128; off <<= 1) {
        int x = (t >= off) ? sh[t - off] : 0;
        __syncthreads();
        sh[t] += x;
        __syncthreads();
    }
    if (t < SCAN_NB) boff[t] = (t == 0) ? 0 : sh[t - 1];
    if (t == 127) rowptr[NTOT] = sh[SCAN_NB - 1];
}

__global__ __launch_bounds__(256) void scan_write(const int* __restrict__ cnt,
                                                  const int* __restrict__ boff,
                                                  int* __restrict__ rowptr,
                                                  int* __restrict__ cursor) {
    __shared__ int wsum[4];
    int tid = threadIdx.x;
    int lane = tid & 63;
    int wave = tid >> 6;
    int base = blockIdx.x * 1024 + tid * 4;

    int e0 = 0, e1 = 0, e2 = 0, e3 = 0;
    if (base + 3 < NTOT) {
        int4 v = *(const int4*)(cnt + base);
        e0 = v.x; e1 = v.y; e2 = v.z; e3 = v.w;
    } else {
        if (base + 0 < NTOT) e0 = cnt[base + 0];
        if (base + 1 < NTOT) e1 = cnt[base + 1];
        if (base + 2 < NTOT) e2 = cnt[base + 2];
    }
    int tsum = e0 + e1 + e2 + e3;

    int s = tsum;
#pragma unroll
    for (int off = 1; off < 64; off <<= 1) {
        int x = __shfl_up(s, off);
        if (lane >= off) s += x;
    }
    if (lane == 63) wsum[wave] = s;
    __syncthreads();
    int woff = 0;
    for (int ww = 0; ww < 4; ++ww)
        if (ww < wave) woff += wsum[ww];
    __syncthreads();
    int excl = boff[blockIdx.x] + woff + (s - tsum);

    int4 r;
    r.x = excl;
    r.y = excl + e0;
    r.z = excl + e0 + e1;
    r.w = excl + e0 + e1 + e2;
    if (base + 3 < NTOT) {
        *(int4*)(rowptr + base) = r;
        *(int4*)(cursor + base) = r;
    } else {
        if (base + 0 < NTOT) { rowptr[base + 0] = r.x; cursor[base + 0] = r.x; }
        if (base + 1 < NTOT) { rowptr[base + 1] = r.y; cursor[base + 1] = r.y; }
        if (base + 2 < NTOT) { rowptr[base + 2] = r.z; cursor[base + 2] = r.z; }
    }
}

__global__ __launch_bounds__(256) void scatter_kernel(const int* __restrict__ rows,
                                                      const int* __restrict__ cols,
                                                      const float* __restrict__ vals,
                                                      int* __restrict__ cursor,
                                                      int* __restrict__ scol,
                                                      float* __restrict__ sval) {
    int e = blockIdx.x * 256 + threadIdx.x;
    if (e >= NNZE) return;
    int r = rows[e];
    int pos = atomicAdd(&cursor[r], 1);
    scol[pos] = cols[e];
    sval[pos] = vals[e];
}

// ---------- SpMM layer (pull, bf16 gathers): one wave per row ----------
__global__ __launch_bounds__(256) void spmm16(const int* __restrict__ rowptr,
                                              const int* __restrict__ scol,
                                              const float* __restrict__ sval,
                                              const ushort_t* __restrict__ cur,
                                              ushort_t* __restrict__ nxt,
                                              float* __restrict__ sum_) {
    int wid = (blockIdx.x * 256 + threadIdx.x) >> 6;
    int lane = threadIdx.x & 63;
    if (wid >= NTOT) return;
    int start = rowptr[wid];
    int end = rowptr[wid + 1];
    float acc = 0.f;
    for (int e0 = start; e0 < end; e0 += 32) {
        int n = min(32, end - e0);
        int c = 0;
        float v = 0.f;
        int sl = lane & 31;
        if (sl < n) {
            c = scol[e0 + sl];
            v = sval[e0 + sl];
        }
        for (int k = 0; k < n; ++k) {
            int ck = __shfl(c, k);
            float vk = __shfl(v, k);
            acc += vk * bf2f(cur[(size_t)ck * DD + lane]);
        }
    }
    size_t o = (size_t)wid * DD + lane;
    nxt[o] = f2bf(acc);
    sum_[o] += acc;
}

// ---------- final gather + dot ----------
__global__ __launch_bounds__(256) void gamma_kernel(const int* __restrict__ users,
                                                    const int* __restrict__ items,
                                                    const float* __restrict__ sum_,
                                                    float* __restrict__ out) {
    int gid = blockIdx.x * 256 + threadIdx.x;
    int b = gid >> 6;
    int lane = gid & 63;
    if (b >= BBATCH) return;
    int u = users[b];
    int it = items[b];
    float pu = sum_[(size_t)u * DD + lane];
    float pi = sum_[(size_t)(NUM_USERS + it) * DD + lane];
    float p = pu * pi;
#pragma unroll
    for (int m = 32; m; m >>= 1) p += __shfl_xor(p, m);
    if (lane == 0) out[b] = p * 0.0625f;
}

extern "C" void kernel_launch(void* const* d_in, const int* in_sizes, int n_in,
                              void* d_out, int out_size, void* d_ws, size_t ws_size,
                              hipStream_t stream) {
    const int* users = (const int*)d_in[0];
    const int* items = (const int*)d_in[1];
    const int* adj = (const int*)d_in[2];
    const int* grows = (const int*)d_in[3];
    const int* gcols = (const int*)d_in[4];
    const float* gvals = (const float*)d_in[5];
    const float* sem = (const float*)d_in[6];
    const float* usem = (const float*)d_in[7];
    const float* emb_user = (const float*)d_in[8];
    const float* emb_item = (const float*)d_in[9];
    const float* W_sem = (const float*)d_in[10];
    const float* b_sem = (const float*)d_in[11];
    const float* W_usem = (const float*)d_in[12];
    const float* b_usem = (const float*)d_in[13];
    const float* W_att = (const float*)d_in[14];
    const float* a_att = (const float*)d_in[15];
    float* out = (float*)d_out;

    const size_t NE = (size_t)NTOT * DD;          // 5.76M
    const size_t IE = (size_t)NUM_ITEMS * DD;     // 1.92M
    char* p = (char*)d_ws;
    float* sum_ = (float*)p;      p += NE * 4;
    ushort_t* cur16 = (ushort_t*)p; p += NE * 2;
    ushort_t* nxt16 = (ushort_t*)p; p += NE * 2;
    float* M0 = (float*)p;        p += IE * 4;
    ushort_t* M0h = (ushort_t*)p; p += IE * 2;
    int* scol = (int*)p;          p += (size_t)NNZE * 4;
    float* sval = (float*)p;      p += (size_t)NNZE * 4;
    ushort_t* WThiU = (ushort_t*)p; p += 65536 * 2;
    ushort_t* WTloU = (ushort_t*)p; p += 65536 * 2;
    ushort_t* WThiS = (ushort_t*)p; p += 65536 * 2;
    ushort_t* WTloS = (ushort_t*)p; p += 65536 * 2;
    float* s1 = (float*)p;        p += NUM_ITEMS * 4;
    float* s2 = (float*)p;        p += NUM_ITEMS * 4;
    float* wa1 = (float*)p;       p += SEMD * 4;
    float* wa2 = (float*)p;       p += SEMD * 4;
    int* cnt = (int*)p;           p += NTOT * 4;
    int* rowptr = (int*)p;        p += (NTOT + 4) * 4;
    int* cursor = (int*)p;        p += NTOT * 4;
    int* bsum = (int*)p;          p += 96 * 4;
    int* boff = (int*)p;          p += 96 * 4;

    prep_wa<<<1, 1024, 0, stream>>>(W_att, a_att, wa1, wa2);
    wsplit<<<512, 256, 0, stream>>>(W_usem, W_sem, WThiU, WTloU, WThiS, WTloS);

    gemm_mfma<false><<<(NUM_USERS + 127) / 128, 256, 0, stream>>>(
        usem, WThiU, WTloU, b_usem, emb_user, sum_, cur16, NUM_USERS,
        nullptr, nullptr, nullptr, nullptr);
    gemm_mfma<true><<<(NUM_ITEMS + 127) / 128, 256, 0, stream>>>(
        sem, WThiS, WTloS, b_sem, emb_item, M0, M0h, NUM_ITEMS,
        wa1, wa2, s1, s2);

    att_kernel<<<(NUM_ITEMS * 64 + 255) / 256, 256, 0, stream>>>(adj, s1, s2, M0, M0h,
                                                                 cur16, sum_);

    hipMemsetAsync(cnt, 0, NTOT * sizeof(int), stream);
    hist_kernel<<<(NNZE + 255) / 256, 256, 0, stream>>>(grows, cnt);
    scan_blocksums<<<SCAN_NB, 256, 0, stream>>>(cnt, bsum);
    scan_bsums<<<1, 128, 0, stream>>>(bsum, boff, rowptr);
    scan_write<<<SCAN_NB, 256, 0, stream>>>(cnt, boff, rowptr, cursor);
    scatter_kernel<<<(NNZE + 255) / 256, 256, 0, stream>>>(grows, gcols, gvals, cursor,
                                                           scol, sval);

    ushort_t* cur = cur16;
    ushort_t* nxt = nxt16;
    for (int l = 0; l < NLAYERS; ++l) {
        spmm16<<<(NTOT * 64 + 255) / 256, 256, 0, stream>>>(rowptr, scol, sval,
                                                            cur, nxt, sum_);
        ushort_t* t = cur;
        cur = nxt;
        nxt = t;
    }
    gamma_kernel<<<(BBATCH * 64 + 255) / 256, 256, 0, stream>>>(users, items, sum_, out);
}

// Round 5
// 552.657 us; speedup vs baseline: 9.7584x; 1.5001x over previous
//
#include <hip/hip_runtime.h>
#include <hip/hip_bf16.h>
#include <math.h>

#define NUM_USERS 60000
#define NUM_ITEMS 30000
#define DD 64
#define SEMD 1024
#define HIDD 32
#define KNBR 32
#define NNZE 2000000
#define NLAYERS 3
#define BBATCH 4096
#define LALPHA 0.2f
#define NTOT (NUM_USERS + NUM_ITEMS)
#define SCAN_NB ((NTOT + 1023) / 1024)  // 88

typedef unsigned short ushort_t;
typedef short s16x8 __attribute__((ext_vector_type(8)));
typedef float f32x4 __attribute__((ext_vector_type(4)));

__device__ __forceinline__ ushort_t f2bf(float x) {  // RNE (used for stored tables)
    unsigned u = __float_as_uint(x);
    return (ushort_t)((u + 0x7FFFu + ((u >> 16) & 1u)) >> 16);
}
__device__ __forceinline__ float bf2f(ushort_t s) {
    return __uint_as_float(((unsigned)s) << 16);
}

#define CFENCE() asm volatile("" ::: "memory")

// ---------- W split (transposed bf16 hi/lo) + fused wa1/wa2 ----------
__global__ __launch_bounds__(256) void wsplit(const float* __restrict__ Wu,
                                              const float* __restrict__ Ws,
                                              ushort_t* __restrict__ hiU, ushort_t* __restrict__ loU,
                                              ushort_t* __restrict__ hiS, ushort_t* __restrict__ loS,
                                              const float* __restrict__ W_att,
                                              const float* __restrict__ a_att,
                                              float* __restrict__ wa1,
                                              float* __restrict__ wa2) {
    if (blockIdx.x == 512) {  // fused prep_wa
        int t = threadIdx.x;
#pragma unroll
        for (int r = 0; r < 4; ++r) {
            int k = t * 4 + r;
            float d1 = 0.f, d2 = 0.f;
#pragma unroll
            for (int h = 0; h < HIDD; ++h) {
                float w = W_att[k * HIDD + h];
                d1 += w * a_att[h];
                d2 += w * a_att[HIDD + h];
            }
            wa1[k] = d1;
            wa2[k] = d2;
        }
        return;
    }
    int id = blockIdx.x * 256 + threadIdx.x;  // 0..131071
    int i = id & 65535;
    int k = i & 1023;
    int c = i >> 10;
    float x = (id < 65536) ? Wu[(size_t)k * DD + c] : Ws[(size_t)k * DD + c];
    ushort_t h = f2bf(x);
    ushort_t l = f2bf(x - bf2f(h));
    ushort_t* dh = (id < 65536) ? hiU : hiS;
    ushort_t* dl = (id < 65536) ? loU : loS;
    dh[(size_t)c * SEMD + k] = h;
    dl[(size_t)c * SEMD + k] = l;
}

// ---------- MFMA bf16x3 GEMM + bias + ELU + merge (+ optional fused s1/s2) ----------
// A:[M,1024] fp32, WT hi/lo:[64][1024] bf16.  out = (emb + elu(A@W+b))*0.5
// BM=64, BK=64, 256 threads (4 waves), each wave 16 rows x 64 cols.
// Register-prefetch next tile; raw s_barrier (no vmcnt drain).
template <bool DOS12>
__global__ __launch_bounds__(256) void gemm_mfma(
    const float* __restrict__ A,
    const ushort_t* __restrict__ WThi,
    const ushort_t* __restrict__ WTlo,
    const float* __restrict__ bias,
    const float* __restrict__ emb,
    float* __restrict__ out32,
    ushort_t* __restrict__ out16,
    int M,
    const float* __restrict__ wa1,
    const float* __restrict__ wa2,
    float* __restrict__ s1,
    float* __restrict__ s2) {
    __shared__ __align__(16) ushort_t Ah[64 * 64];   // swizzled: byte ^= (row&7)<<4
    __shared__ __align__(16) ushort_t Alo[64 * 64];
    __shared__ __align__(16) ushort_t Wh[64 * 64];
    __shared__ __align__(16) ushort_t Wl[64 * 64];

    const int tid = threadIdx.x;
    const int lane = tid & 63;
    const int w = tid >> 6;
    const int l15 = lane & 15;
    const int l4 = lane >> 4;
    const int row0 = blockIdx.x * 64;

    f32x4 acc[4] = {};
    float s1p[4] = {}, s2p[4] = {};

    const int srow = tid >> 4;   // 0..15
    const int sc = tid & 15;     // 16-float4 chunks across k=64
    const int wcol = tid >> 2;   // 0..63
    const int wq = tid & 3;

    float4 rA[4];
    s16x8 rWh[2], rWl[2];

    auto loadT = [&](int kt) {
        const int k0 = kt * 64;
#pragma unroll
        for (int p = 0; p < 4; ++p) {
            int grow = row0 + p * 16 + srow;
            rA[p] = make_float4(0.f, 0.f, 0.f, 0.f);
            if (grow < M) rA[p] = *(const float4*)(A + (size_t)grow * SEMD + k0 + sc * 4);
        }
        const ushort_t* sh = WThi + (size_t)wcol * SEMD + k0 + wq * 16;
        const ushort_t* sl = WTlo + (size_t)wcol * SEMD + k0 + wq * 16;
        rWh[0] = *(const s16x8*)sh;
        rWh[1] = *(const s16x8*)(sh + 8);
        rWl[0] = *(const s16x8*)sl;
        rWl[1] = *(const s16x8*)(sl + 8);
    };

    loadT(0);

    for (int kt = 0; kt < 16; ++kt) {
        float4 va1w, va2w;
        if (DOS12) {
            va1w = *(const float4*)(wa1 + kt * 64 + sc * 4);
            va2w = *(const float4*)(wa2 + kt * 64 + sc * 4);
        }
        CFENCE();
        __builtin_amdgcn_s_barrier();   // LDS consumable (prev tile's reads done)
        CFENCE();
        // ---- convert + write LDS (truncation split: a = hi + lo + O(2^-16)) ----
#pragma unroll
        for (int p = 0; p < 4; ++p) {
            float4 v = rA[p];
            if (DOS12) {
                s1p[p] += v.x * va1w.x + v.y * va1w.y + v.z * va1w.z + v.w * va1w.w;
                s2p[p] += v.x * va2w.x + v.y * va2w.y + v.z * va2w.z + v.w * va2w.w;
            }
            unsigned ux = __float_as_uint(v.x), uy = __float_as_uint(v.y);
            unsigned uz = __float_as_uint(v.z), uw = __float_as_uint(v.w);
            ushort4 hv, lv;
            hv.x = (ushort_t)(ux >> 16); hv.y = (ushort_t)(uy >> 16);
            hv.z = (ushort_t)(uz >> 16); hv.w = (ushort_t)(uw >> 16);
            lv.x = (ushort_t)(__float_as_uint(v.x - __uint_as_float(ux & 0xFFFF0000u)) >> 16);
            lv.y = (ushort_t)(__float_as_uint(v.y - __uint_as_float(uy & 0xFFFF0000u)) >> 16);
            lv.z = (ushort_t)(__float_as_uint(v.z - __uint_as_float(uz & 0xFFFF0000u)) >> 16);
            lv.w = (ushort_t)(__float_as_uint(v.w - __uint_as_float(uw & 0xFFFF0000u)) >> 16);
            int rin = p * 16 + srow;
            int boff = rin * 128 + ((sc * 8) ^ ((rin & 7) << 4));
            *(ushort4*)((char*)Ah + boff) = hv;
            *(ushort4*)((char*)Alo + boff) = lv;
        }
        {
            char* dh = (char*)Wh + wcol * 128;
            char* dl = (char*)Wl + wcol * 128;
            int sw = (wcol & 7) << 4;
            *(s16x8*)(dh + ((wq * 32) ^ sw)) = rWh[0];
            *(s16x8*)(dh + ((wq * 32 + 16) ^ sw)) = rWh[1];
            *(s16x8*)(dl + ((wq * 32) ^ sw)) = rWl[0];
            *(s16x8*)(dl + ((wq * 32 + 16) ^ sw)) = rWl[1];
        }
        // ---- prefetch next tile (stays in flight across the barrier) ----
        if (kt < 15) loadT(kt + 1);
        asm volatile("s_waitcnt lgkmcnt(0)" ::: "memory");
        __builtin_amdgcn_s_barrier();   // LDS tile visible to all waves
        CFENCE();

        // ---- fragments + MFMA ----
        s16x8 fah[2], fal[2];
#pragma unroll
        for (int kf = 0; kf < 2; ++kf) {
            int row = w * 16 + l15;
            int bc = kf * 64 + l4 * 16;
            int off = row * 128 + (bc ^ ((row & 7) << 4));
            fah[kf] = *(const s16x8*)((const char*)Ah + off);
            fal[kf] = *(const s16x8*)((const char*)Alo + off);
        }
#pragma unroll
        for (int cg = 0; cg < 4; ++cg) {
            s16x8 fwh[2], fwl[2];
#pragma unroll
            for (int kf = 0; kf < 2; ++kf) {
                int col = cg * 16 + l15;
                int bc = kf * 64 + l4 * 16;
                int off = col * 128 + (bc ^ ((col & 7) << 4));
                fwh[kf] = *(const s16x8*)((const char*)Wh + off);
                fwl[kf] = *(const s16x8*)((const char*)Wl + off);
            }
#pragma unroll
            for (int kf = 0; kf < 2; ++kf) {
                acc[cg] = __builtin_amdgcn_mfma_f32_16x16x32_bf16(fah[kf], fwh[kf], acc[cg], 0, 0, 0);
                acc[cg] = __builtin_amdgcn_mfma_f32_16x16x32_bf16(fah[kf], fwl[kf], acc[cg], 0, 0, 0);
                acc[cg] = __builtin_amdgcn_mfma_f32_16x16x32_bf16(fal[kf], fwh[kf], acc[cg], 0, 0, 0);
            }
        }
    }

    // ---- fused s1/s2 reduce (16 consecutive lanes share one row) ----
    if (DOS12) {
#pragma unroll
        for (int p = 0; p < 4; ++p) {
            float v1 = s1p[p], v2 = s2p[p];
#pragma unroll
            for (int m = 1; m < 16; m <<= 1) {
                v1 += __shfl_xor(v1, m);
                v2 += __shfl_xor(v2, m);
            }
            int grow = row0 + p * 16 + srow;
            if (sc == 0 && grow < M) {
                s1[grow] = v1;
                s2[grow] = v2;
            }
        }
    }

    // ---- epilogue: D col=lane&15, row=(lane>>4)*4+j ----
#pragma unroll
    for (int cg = 0; cg < 4; ++cg) {
        int col = cg * 16 + l15;
        float b = bias[col];
#pragma unroll
        for (int j = 0; j < 4; ++j) {
            int grow = row0 + w * 16 + l4 * 4 + j;
            if (grow < M) {
                float x = acc[cg][j] + b;
                float e = x > 0.f ? x : (expf(x) - 1.f);
                float v = (emb[(size_t)grow * DD + col] + e) * 0.5f;
                out32[(size_t)grow * DD + col] = v;
                out16[(size_t)grow * DD + col] = f2bf(v);
            }
        }
    }
}

// ---------- attention + h' + merge: one wave per item row ----------
__global__ __launch_bounds__(256) void att_kernel(const int* __restrict__ adj,
                                                  const float* __restrict__ s1,
                                                  const float* __restrict__ s2,
                                                  const float* __restrict__ M0,
                                                  const ushort_t* __restrict__ M0h,
                                                  ushort_t* __restrict__ cur16,
                                                  float* __restrict__ sum_) {
    int gid = blockIdx.x * 256 + threadIdx.x;
    int row = gid >> 6;
    int lane = gid & 63;
    if (row >= NUM_ITEMS) return;
    int kk = lane & 31;
    int col = adj[(size_t)row * KNBR + kk];
    float e = s1[col] + s2[row];
    e = e > 0.f ? e : LALPHA * e;
    float mx = e;
#pragma unroll
    for (int m = 1; m < 32; m <<= 1) mx = fmaxf(mx, __shfl_xor(mx, m));
    float ex = expf(e - mx);
    float ssum = ex;
#pragma unroll
    for (int m = 1; m < 32; m <<= 1) ssum += __shfl_xor(ssum, m);
    float wgt = ex / ssum;
    float h = 0.f;
#pragma unroll
    for (int k = 0; k < 32; ++k) {
        int ck = __builtin_amdgcn_readlane(col, k);  // wave-uniform -> SGPR
        float wk = __uint_as_float((unsigned)__builtin_amdgcn_readlane(
            (int)__float_as_uint(wgt), k));
        h += wk * bf2f(M0h[(size_t)ck * DD + lane]);
    }
    float eh = h > 0.f ? h : (expf(h) - 1.f);
    float v = (M0[(size_t)row * DD + lane] + eh) * 0.5f;
    size_t o = (size_t)(NUM_USERS + row) * DD + lane;
    cur16[o] = f2bf(v);
    sum_[o] = v;
}

// ---------- CSR build ----------
__global__ __launch_bounds__(256) void hist_kernel(const int* __restrict__ rows,
                                                   int* __restrict__ cnt) {
    int e = blockIdx.x * 256 + threadIdx.x;
    if (e < NNZE) atomicAdd(&cnt[rows[e]], 1);
}

__global__ __launch_bounds__(256) void scan_blocksums(const int* __restrict__ cnt,
                                                      int* __restrict__ bsum) {
    __shared__ int ws[4];
    int tid = threadIdx.x;
    int base = blockIdx.x * 1024 + tid * 4;
    int s = 0;
    if (base + 3 < NTOT) {
        int4 v = *(const int4*)(cnt + base);
        s = v.x + v.y + v.z + v.w;
    } else {
        for (int i = 0; i < 4; ++i)
            if (base + i < NTOT) s += cnt[base + i];
    }
#pragma unroll
    for (int m = 32; m; m >>= 1) s += __shfl_xor(s, m);
    if ((tid & 63) == 0) ws[tid >> 6] = s;
    __syncthreads();
    if (tid == 0) bsum[blockIdx.x] = ws[0] + ws[1] + ws[2] + ws[3];
}

__global__ __launch_bounds__(128) void scan_bsums(const int* __restrict__ bsum,
                                                  int* __restrict__ boff,
                                                  int* __restrict__ rowptr) {
    __shared__ int sh[128];
    int t = threadIdx.x;
    int v = (t < SCAN_NB) ? bsum[t] : 0;
    sh[t] = v;
    __syncthreads();
    for (int off = 1; off < 128; off <<= 1) {
        int x = (t >= off) ? sh[t - off] : 0;
        __syncthreads();
        sh[t] += x;
        __syncthreads();
    }
    if (t < SCAN_NB) boff[t] = (t == 0) ? 0 : sh[t - 1];
    if (t == 127) rowptr[NTOT] = sh[SCAN_NB - 1];
}

__global__ __launch_bounds__(256) void scan_write(const int* __restrict__ cnt,
                                                  const int* __restrict__ boff,
                                                  int* __restrict__ rowptr,
                                                  int* __restrict__ cursor) {
    __shared__ int wsum[4];
    int tid = threadIdx.x;
    int lane = tid & 63;
    int wave = tid >> 6;
    int base = blockIdx.x * 1024 + tid * 4;

    int e0 = 0, e1 = 0, e2 = 0, e3 = 0;
    if (base + 3 < NTOT) {
        int4 v = *(const int4*)(cnt + base);
        e0 = v.x; e1 = v.y; e2 = v.z; e3 = v.w;
    } else {
        if (base + 0 < NTOT) e0 = cnt[base + 0];
        if (base + 1 < NTOT) e1 = cnt[base + 1];
        if (base + 2 < NTOT) e2 = cnt[base + 2];
    }
    int tsum = e0 + e1 + e2 + e3;

    int s = tsum;
#pragma unroll
    for (int off = 1; off < 64; off <<= 1) {
        int x = __shfl_up(s, off);
        if (lane >= off) s += x;
    }
    if (lane == 63) wsum[wave] = s;
    __syncthreads();
    int woff = 0;
    for (int ww = 0; ww < 4; ++ww)
        if (ww < wave) woff += wsum[ww];
    __syncthreads();
    int excl = boff[blockIdx.x] + woff + (s - tsum);

    int4 r;
    r.x = excl;
    r.y = excl + e0;
    r.z = excl + e0 + e1;
    r.w = excl + e0 + e1 + e2;
    if (base + 3 < NTOT) {
        *(int4*)(rowptr + base) = r;
        *(int4*)(cursor + base) = r;
    } else {
        if (base + 0 < NTOT) { rowptr[base + 0] = r.x; cursor[base + 0] = r.x; }
        if (base + 1 < NTOT) { rowptr[base + 1] = r.y; cursor[base + 1] = r.y; }
        if (base + 2 < NTOT) { rowptr[base + 2] = r.z; cursor[base + 2] = r.z; }
    }
}

__global__ __launch_bounds__(256) void scatter_kernel(const int* __restrict__ rows,
                                                      const int* __restrict__ cols,
                                                      const float* __restrict__ vals,
                                                      int* __restrict__ cursor,
                                                      int2* __restrict__ sedge) {
    int e = blockIdx.x * 256 + threadIdx.x;
    if (e >= NNZE) return;
    int r = rows[e];
    int pos = atomicAdd(&cursor[r], 1);
    sedge[pos] = make_int2(cols[e], __float_as_int(vals[e]));
}

// ---------- SpMM layer (pull, scalar edge loads): one wave per row ----------
__global__ __launch_bounds__(256) void spmm16(const int* __restrict__ rowptr,
                                              const int2* __restrict__ sedge,
                                              const ushort_t* __restrict__ cur,
                                              ushort_t* __restrict__ nxt,
                                              float* __restrict__ sum_) {
    int row = __builtin_amdgcn_readfirstlane((blockIdx.x * 256 + threadIdx.x) >> 6);
    int lane = threadIdx.x & 63;
    if (row >= NTOT) return;
    int i = rowptr[row];
    int e = rowptr[row + 1];
    float acc = 0.f;
    for (; i + 4 <= e; i += 4) {
        int2 ed0 = sedge[i];
        int2 ed1 = sedge[i + 1];
        int2 ed2 = sedge[i + 2];
        int2 ed3 = sedge[i + 3];
        float x0 = bf2f(cur[(size_t)ed0.x * DD + lane]);
        float x1 = bf2f(cur[(size_t)ed1.x * DD + lane]);
        float x2 = bf2f(cur[(size_t)ed2.x * DD + lane]);
        float x3 = bf2f(cur[(size_t)ed3.x * DD + lane]);
        acc += __int_as_float(ed0.y) * x0;
        acc += __int_as_float(ed1.y) * x1;
        acc += __int_as_float(ed2.y) * x2;
        acc += __int_as_float(ed3.y) * x3;
    }
    for (; i < e; ++i) {
        int2 ed = sedge[i];
        acc += __int_as_float(ed.y) * bf2f(cur[(size_t)ed.x * DD + lane]);
    }
    size_t o = (size_t)row * DD + lane;
    nxt[o] = f2bf(acc);
    sum_[o] += acc;
}

// ---------- final gather + dot ----------
__global__ __launch_bounds__(256) void gamma_kernel(const int* __restrict__ users,
                                                    const int* __restrict__ items,
                                                    const float* __restrict__ sum_,
                                                    float* __restrict__ out) {
    int gid = blockIdx.x * 256 + threadIdx.x;
    int b = gid >> 6;
    int lane = gid & 63;
    if (b >= BBATCH) return;
    int u = users[b];
    int it = items[b];
    float pu = sum_[(size_t)u * DD + lane];
    float pi = sum_[(size_t)(NUM_USERS + it) * DD + lane];
    float p = pu * pi;
#pragma unroll
    for (int m = 32; m; m >>= 1) p += __shfl_xor(p, m);
    if (lane == 0) out[b] = p * 0.0625f;
}

extern "C" void kernel_launch(void* const* d_in, const int* in_sizes, int n_in,
                              void* d_out, int out_size, void* d_ws, size_t ws_size,
                              hipStream_t stream) {
    const int* users = (const int*)d_in[0];
    const int* items = (const int*)d_in[1];
    const int* adj = (const int*)d_in[2];
    const int* grows = (const int*)d_in[3];
    const int* gcols = (const int*)d_in[4];
    const float* gvals = (const float*)d_in[5];
    const float* sem = (const float*)d_in[6];
    const float* usem = (const float*)d_in[7];
    const float* emb_user = (const float*)d_in[8];
    const float* emb_item = (const float*)d_in[9];
    const float* W_sem = (const float*)d_in[10];
    const float* b_sem = (const float*)d_in[11];
    const float* W_usem = (const float*)d_in[12];
    const float* b_usem = (const float*)d_in[13];
    const float* W_att = (const float*)d_in[14];
    const float* a_att = (const float*)d_in[15];
    float* out = (float*)d_out;

    const size_t NE = (size_t)NTOT * DD;          // 5.76M
    const size_t IE = (size_t)NUM_ITEMS * DD;     // 1.92M
    char* p = (char*)d_ws;
    float* sum_ = (float*)p;        p += NE * 4;
    ushort_t* cur16 = (ushort_t*)p; p += NE * 2;
    ushort_t* nxt16 = (ushort_t*)p; p += NE * 2;
    float* M0 = (float*)p;          p += IE * 4;
    ushort_t* M0h = (ushort_t*)p;   p += IE * 2;
    int2* sedge = (int2*)p;         p += (size_t)NNZE * 8;
    ushort_t* WThiU = (ushort_t*)p; p += 65536 * 2;
    ushort_t* WTloU = (ushort_t*)p; p += 65536 * 2;
    ushort_t* WThiS = (ushort_t*)p; p += 65536 * 2;
    ushort_t* WTloS = (ushort_t*)p; p += 65536 * 2;
    float* s1 = (float*)p;          p += NUM_ITEMS * 4;
    float* s2 = (float*)p;          p += NUM_ITEMS * 4;
    float* wa1 = (float*)p;         p += SEMD * 4;
    float* wa2 = (float*)p;         p += SEMD * 4;
    int* cnt = (int*)p;             p += NTOT * 4;
    int* rowptr = (int*)p;          p += (NTOT + 4) * 4;
    int* cursor = (int*)p;          p += NTOT * 4;
    int* bsum = (int*)p;            p += 96 * 4;
    int* boff = (int*)p;            p += 96 * 4;

    wsplit<<<513, 256, 0, stream>>>(W_usem, W_sem, WThiU, WTloU, WThiS, WTloS,
                                    W_att, a_att, wa1, wa2);

    gemm_mfma<false><<<(NUM_USERS + 63) / 64, 256, 0, stream>>>(
        usem, WThiU, WTloU, b_usem, emb_user, sum_, cur16, NUM_USERS,
        nullptr, nullptr, nullptr, nullptr);
    gemm_mfma<true><<<(NUM_ITEMS + 63) / 64, 256, 0, stream>>>(
        sem, WThiS, WTloS, b_sem, emb_item, M0, M0h, NUM_ITEMS,
        wa1, wa2, s1, s2);

    att_kernel<<<(NUM_ITEMS * 64 + 255) / 256, 256, 0, stream>>>(adj, s1, s2, M0, M0h,
                                                                 cur16, sum_);

    hipMemsetAsync(cnt, 0, NTOT * sizeof(int), stream);
    hist_kernel<<<(NNZE + 255) / 256, 256, 0, stream>>>(grows, cnt);
    scan_blocksums<<<SCAN_NB, 256, 0, stream>>>(cnt, bsum);
    scan_bsums<<<1, 128, 0, stream>>>(bsum, boff, rowptr);
    scan_write<<<SCAN_NB, 256, 0, stream>>>(cnt, boff, rowptr, cursor);
    scatter_kernel<<<(NNZE + 255) / 256, 256, 0, stream>>>(grows, gcols, gvals, cursor,
                                                           sedge);

    ushort_t* cur = cur16;
    ushort_t* nxt = nxt16;
    for (int l = 0; l < NLAYERS; ++l) {
        spmm16<<<(NTOT * 64 + 255) / 256, 256, 0, stream>>>(rowptr, sedge, cur, nxt, sum_);
        ushort_t* t = cur;
        cur = nxt;
        nxt = t;
    }
    gamma_kernel<<<(BBATCH * 64 + 255) / 256, 256, 0, stream>>>(users, items, sum_, out);
}

// Round 6
// 513.133 us; speedup vs baseline: 10.5100x; 1.0770x over previous
//
#include <hip/hip_runtime.h>
#include <hip/hip_bf16.h>
#include <math.h>

#define NUM_USERS 60000
#define NUM_ITEMS 30000
#define DD 64
#define SEMD 1024
#define HIDD 32
#define KNBR 32
#define NNZE 2000000
#define NLAYERS 3
#define BBATCH 4096
#define LALPHA 0.2f
#define NTOT (NUM_USERS + NUM_ITEMS)
#define SCAN_NB ((NTOT + 1023) / 1024)  // 88
#define NBKT 704                         // buckets = row>>7 (90000/128)
#define BCAP 3328                        // bucket LDS cap (+9 sigma)

typedef unsigned short ushort_t;
typedef short s16x8 __attribute__((ext_vector_type(8)));
typedef float f32x4 __attribute__((ext_vector_type(4)));

__device__ __forceinline__ ushort_t f2bf(float x) {  // RNE (used for stored tables)
    unsigned u = __float_as_uint(x);
    return (ushort_t)((u + 0x7FFFu + ((u >> 16) & 1u)) >> 16);
}
__device__ __forceinline__ float bf2f(ushort_t s) {
    return __uint_as_float(((unsigned)s) << 16);
}

#define CFENCE() asm volatile("" ::: "memory")

// ---------- W split (transposed bf16 hi/lo) + fused wa1/wa2 ----------
__global__ __launch_bounds__(256) void wsplit(const float* __restrict__ Wu,
                                              const float* __restrict__ Ws,
                                              ushort_t* __restrict__ hiU, ushort_t* __restrict__ loU,
                                              ushort_t* __restrict__ hiS, ushort_t* __restrict__ loS,
                                              const float* __restrict__ W_att,
                                              const float* __restrict__ a_att,
                                              float* __restrict__ wa1,
                                              float* __restrict__ wa2) {
    if (blockIdx.x == 512) {  // fused prep_wa
        int t = threadIdx.x;
#pragma unroll
        for (int r = 0; r < 4; ++r) {
            int k = t * 4 + r;
            float d1 = 0.f, d2 = 0.f;
#pragma unroll
            for (int h = 0; h < HIDD; ++h) {
                float w = W_att[k * HIDD + h];
                d1 += w * a_att[h];
                d2 += w * a_att[HIDD + h];
            }
            wa1[k] = d1;
            wa2[k] = d2;
        }
        return;
    }
    int id = blockIdx.x * 256 + threadIdx.x;  // 0..131071
    int i = id & 65535;
    int k = i & 1023;
    int c = i >> 10;
    float x = (id < 65536) ? Wu[(size_t)k * DD + c] : Ws[(size_t)k * DD + c];
    ushort_t h = f2bf(x);
    ushort_t l = f2bf(x - bf2f(h));
    ushort_t* dh = (id < 65536) ? hiU : hiS;
    ushort_t* dl = (id < 65536) ? loU : loS;
    dh[(size_t)c * SEMD + k] = h;
    dl[(size_t)c * SEMD + k] = l;
}

// ---------- MFMA bf16x3 GEMM + bias + ELU + merge (+ optional fused s1/s2) ----------
template <bool DOS12>
__global__ __launch_bounds__(256) void gemm_mfma(
    const float* __restrict__ A,
    const ushort_t* __restrict__ WThi,
    const ushort_t* __restrict__ WTlo,
    const float* __restrict__ bias,
    const float* __restrict__ emb,
    float* __restrict__ out32,
    ushort_t* __restrict__ out16,
    int M,
    const float* __restrict__ wa1,
    const float* __restrict__ wa2,
    float* __restrict__ s1,
    float* __restrict__ s2) {
    __shared__ __align__(16) ushort_t Ah[64 * 64];   // swizzled: byte ^= (row&7)<<4
    __shared__ __align__(16) ushort_t Alo[64 * 64];
    __shared__ __align__(16) ushort_t Wh[64 * 64];
    __shared__ __align__(16) ushort_t Wl[64 * 64];

    const int tid = threadIdx.x;
    const int lane = tid & 63;
    const int w = tid >> 6;
    const int l15 = lane & 15;
    const int l4 = lane >> 4;
    const int row0 = blockIdx.x * 64;

    f32x4 acc[4] = {};
    float s1p[4] = {}, s2p[4] = {};

    const int srow = tid >> 4;   // 0..15
    const int sc = tid & 15;     // 16-float4 chunks across k=64
    const int wcol = tid >> 2;   // 0..63
    const int wq = tid & 3;

    float4 rA[4];
    s16x8 rWh[2], rWl[2];

    auto loadT = [&](int kt) {
        const int k0 = kt * 64;
#pragma unroll
        for (int p = 0; p < 4; ++p) {
            int grow = row0 + p * 16 + srow;
            rA[p] = make_float4(0.f, 0.f, 0.f, 0.f);
            if (grow < M) rA[p] = *(const float4*)(A + (size_t)grow * SEMD + k0 + sc * 4);
        }
        const ushort_t* sh = WThi + (size_t)wcol * SEMD + k0 + wq * 16;
        const ushort_t* sl = WTlo + (size_t)wcol * SEMD + k0 + wq * 16;
        rWh[0] = *(const s16x8*)sh;
        rWh[1] = *(const s16x8*)(sh + 8);
        rWl[0] = *(const s16x8*)sl;
        rWl[1] = *(const s16x8*)(sl + 8);
    };

    loadT(0);

    for (int kt = 0; kt < 16; ++kt) {
        float4 va1w, va2w;
        if (DOS12) {
            va1w = *(const float4*)(wa1 + kt * 64 + sc * 4);
            va2w = *(const float4*)(wa2 + kt * 64 + sc * 4);
        }
        CFENCE();
        __builtin_amdgcn_s_barrier();   // LDS consumable (prev tile's reads done)
        CFENCE();
#pragma unroll
        for (int p = 0; p < 4; ++p) {
            float4 v = rA[p];
            if (DOS12) {
                s1p[p] += v.x * va1w.x + v.y * va1w.y + v.z * va1w.z + v.w * va1w.w;
                s2p[p] += v.x * va2w.x + v.y * va2w.y + v.z * va2w.z + v.w * va2w.w;
            }
            unsigned ux = __float_as_uint(v.x), uy = __float_as_uint(v.y);
            unsigned uz = __float_as_uint(v.z), uw = __float_as_uint(v.w);
            ushort4 hv, lv;
            hv.x = (ushort_t)(ux >> 16); hv.y = (ushort_t)(uy >> 16);
            hv.z = (ushort_t)(uz >> 16); hv.w = (ushort_t)(uw >> 16);
            lv.x = (ushort_t)(__float_as_uint(v.x - __uint_as_float(ux & 0xFFFF0000u)) >> 16);
            lv.y = (ushort_t)(__float_as_uint(v.y - __uint_as_float(uy & 0xFFFF0000u)) >> 16);
            lv.z = (ushort_t)(__float_as_uint(v.z - __uint_as_float(uz & 0xFFFF0000u)) >> 16);
            lv.w = (ushort_t)(__float_as_uint(v.w - __uint_as_float(uw & 0xFFFF0000u)) >> 16);
            int rin = p * 16 + srow;
            int boff = rin * 128 + ((sc * 8) ^ ((rin & 7) << 4));
            *(ushort4*)((char*)Ah + boff) = hv;
            *(ushort4*)((char*)Alo + boff) = lv;
        }
        {
            char* dh = (char*)Wh + wcol * 128;
            char* dl = (char*)Wl + wcol * 128;
            int sw = (wcol & 7) << 4;
            *(s16x8*)(dh + ((wq * 32) ^ sw)) = rWh[0];
            *(s16x8*)(dh + ((wq * 32 + 16) ^ sw)) = rWh[1];
            *(s16x8*)(dl + ((wq * 32) ^ sw)) = rWl[0];
            *(s16x8*)(dl + ((wq * 32 + 16) ^ sw)) = rWl[1];
        }
        if (kt < 15) loadT(kt + 1);
        asm volatile("s_waitcnt lgkmcnt(0)" ::: "memory");
        __builtin_amdgcn_s_barrier();   // LDS tile visible to all waves
        CFENCE();

        s16x8 fah[2], fal[2];
#pragma unroll
        for (int kf = 0; kf < 2; ++kf) {
            int row = w * 16 + l15;
            int bc = kf * 64 + l4 * 16;
            int off = row * 128 + (bc ^ ((row & 7) << 4));
            fah[kf] = *(const s16x8*)((const char*)Ah + off);
            fal[kf] = *(const s16x8*)((const char*)Alo + off);
        }
#pragma unroll
        for (int cg = 0; cg < 4; ++cg) {
            s16x8 fwh[2], fwl[2];
#pragma unroll
            for (int kf = 0; kf < 2; ++kf) {
                int col = cg * 16 + l15;
                int bc = kf * 64 + l4 * 16;
                int off = col * 128 + (bc ^ ((col & 7) << 4));
                fwh[kf] = *(const s16x8*)((const char*)Wh + off);
                fwl[kf] = *(const s16x8*)((const char*)Wl + off);
            }
#pragma unroll
            for (int kf = 0; kf < 2; ++kf) {
                acc[cg] = __builtin_amdgcn_mfma_f32_16x16x32_bf16(fah[kf], fwh[kf], acc[cg], 0, 0, 0);
                acc[cg] = __builtin_amdgcn_mfma_f32_16x16x32_bf16(fah[kf], fwl[kf], acc[cg], 0, 0, 0);
                acc[cg] = __builtin_amdgcn_mfma_f32_16x16x32_bf16(fal[kf], fwh[kf], acc[cg], 0, 0, 0);
            }
        }
    }

    if (DOS12) {
#pragma unroll
        for (int p = 0; p < 4; ++p) {
            float v1 = s1p[p], v2 = s2p[p];
#pragma unroll
            for (int m = 1; m < 16; m <<= 1) {
                v1 += __shfl_xor(v1, m);
                v2 += __shfl_xor(v2, m);
            }
            int grow = row0 + p * 16 + srow;
            if (sc == 0 && grow < M) {
                s1[grow] = v1;
                s2[grow] = v2;
            }
        }
    }

#pragma unroll
    for (int cg = 0; cg < 4; ++cg) {
        int col = cg * 16 + l15;
        float b = bias[col];
#pragma unroll
        for (int j = 0; j < 4; ++j) {
            int grow = row0 + w * 16 + l4 * 4 + j;
            if (grow < M) {
                float x = acc[cg][j] + b;
                float e = x > 0.f ? x : (expf(x) - 1.f);
                float v = (emb[(size_t)grow * DD + col] + e) * 0.5f;
                out32[(size_t)grow * DD + col] = v;
                out16[(size_t)grow * DD + col] = f2bf(v);
            }
        }
    }
}

// ---------- attention + h' + merge: one wave per item row ----------
__global__ __launch_bounds__(256) void att_kernel(const int* __restrict__ adj,
                                                  const float* __restrict__ s1,
                                                  const float* __restrict__ s2,
                                                  const float* __restrict__ M0,
                                                  const ushort_t* __restrict__ M0h,
                                                  ushort_t* __restrict__ cur16,
                                                  float* __restrict__ sum_) {
    int gid = blockIdx.x * 256 + threadIdx.x;
    int row = gid >> 6;
    int lane = gid & 63;
    if (row >= NUM_ITEMS) return;
    int kk = lane & 31;
    int col = adj[(size_t)row * KNBR + kk];
    float e = s1[col] + s2[row];
    e = e > 0.f ? e : LALPHA * e;
    float mx = e;
#pragma unroll
    for (int m = 1; m < 32; m <<= 1) mx = fmaxf(mx, __shfl_xor(mx, m));
    float ex = expf(e - mx);
    float ssum = ex;
#pragma unroll
    for (int m = 1; m < 32; m <<= 1) ssum += __shfl_xor(ssum, m);
    float wgt = ex / ssum;
    float h = 0.f;
#pragma unroll
    for (int k = 0; k < 32; ++k) {
        int ck = __builtin_amdgcn_readlane(col, k);
        float wk = __uint_as_float((unsigned)__builtin_amdgcn_readlane(
            (int)__float_as_uint(wgt), k));
        h += wk * bf2f(M0h[(size_t)ck * DD + lane]);
    }
    float eh = h > 0.f ? h : (expf(h) - 1.f);
    float v = (M0[(size_t)row * DD + lane] + eh) * 0.5f;
    size_t o = (size_t)(NUM_USERS + row) * DD + lane;
    cur16[o] = f2bf(v);
    sum_[o] = v;
}

// ---------- CSR build ----------
__global__ __launch_bounds__(256) void hist_kernel(const int* __restrict__ rows,
                                                   int* __restrict__ cnt) {
    int e = blockIdx.x * 256 + threadIdx.x;
    if (e < NNZE) atomicAdd(&cnt[rows[e]], 1);
}

__global__ __launch_bounds__(256) void scan_blocksums(const int* __restrict__ cnt,
                                                      int* __restrict__ bsum) {
    __shared__ int ws[4];
    int tid = threadIdx.x;
    int base = blockIdx.x * 1024 + tid * 4;
    int s = 0;
    if (base + 3 < NTOT) {
        int4 v = *(const int4*)(cnt + base);
        s = v.x + v.y + v.z + v.w;
    } else {
        for (int i = 0; i < 4; ++i)
            if (base + i < NTOT) s += cnt[base + i];
    }
#pragma unroll
    for (int m = 32; m; m >>= 1) s += __shfl_xor(s, m);
    if ((tid & 63) == 0) ws[tid >> 6] = s;
    __syncthreads();
    if (tid == 0) bsum[blockIdx.x] = ws[0] + ws[1] + ws[2] + ws[3];
}

__global__ __launch_bounds__(128) void scan_bsums(const int* __restrict__ bsum,
                                                  int* __restrict__ boff,
                                                  int* __restrict__ rowptr) {
    __shared__ int sh[128];
    int t = threadIdx.x;
    int v = (t < SCAN_NB) ? bsum[t] : 0;
    sh[t] = v;
    __syncthreads();
    for (int off = 1; off < 128; off <<= 1) {
        int x = (t >= off) ? sh[t - off] : 0;
        __syncthreads();
        sh[t] += x;
        __syncthreads();
    }
    if (t < SCAN_NB) boff[t] = (t == 0) ? 0 : sh[t - 1];
    if (t == 127) rowptr[NTOT] = sh[SCAN_NB - 1];
}

__global__ __launch_bounds__(256) void scan_write(const int* __restrict__ cnt,
                                                  const int* __restrict__ boff,
                                                  int* __restrict__ rowptr,
                                                  int* __restrict__ cursor,
                                                  int* __restrict__ bcursor) {
    __shared__ int wsum[4];
    int tid = threadIdx.x;
    int lane = tid & 63;
    int wave = tid >> 6;
    int base = blockIdx.x * 1024 + tid * 4;

    int e0 = 0, e1 = 0, e2 = 0, e3 = 0;
    if (base + 3 < NTOT) {
        int4 v = *(const int4*)(cnt + base);
        e0 = v.x; e1 = v.y; e2 = v.z; e3 = v.w;
    } else {
        if (base + 0 < NTOT) e0 = cnt[base + 0];
        if (base + 1 < NTOT) e1 = cnt[base + 1];
        if (base + 2 < NTOT) e2 = cnt[base + 2];
    }
    int tsum = e0 + e1 + e2 + e3;

    int s = tsum;
#pragma unroll
    for (int off = 1; off < 64; off <<= 1) {
        int x = __shfl_up(s, off);
        if (lane >= off) s += x;
    }
    if (lane == 63) wsum[wave] = s;
    __syncthreads();
    int woff = 0;
    for (int ww = 0; ww < 4; ++ww)
        if (ww < wave) woff += wsum[ww];
    __syncthreads();
    int excl = boff[blockIdx.x] + woff + (s - tsum);

    int4 r;
    r.x = excl;
    r.y = excl + e0;
    r.z = excl + e0 + e1;
    r.w = excl + e0 + e1 + e2;
    if (base + 3 < NTOT) {
        *(int4*)(rowptr + base) = r;
        *(int4*)(cursor + base) = r;
    } else {
        if (base + 0 < NTOT) { rowptr[base + 0] = r.x; cursor[base + 0] = r.x; }
        if (base + 1 < NTOT) { rowptr[base + 1] = r.y; cursor[base + 1] = r.y; }
        if (base + 2 < NTOT) { rowptr[base + 2] = r.z; cursor[base + 2] = r.z; }
    }
    // bucket bases for binA (rows at multiples of 128; only i=0 can hit)
    if ((base & 127) == 0 && base < NTOT) bcursor[base >> 7] = r.x;
}

// ---------- Phase A: bin edges by row>>7, grouped writes ----------
__global__ __launch_bounds__(256) void binA(const int* __restrict__ grows,
                                            const int* __restrict__ gcols,
                                            const float* __restrict__ gvals,
                                            int* __restrict__ bcursor,
                                            int2* __restrict__ temp) {
    __shared__ int hist[NBKT];
    __shared__ int gcur[NBKT];
    int tid = threadIdx.x;
    int base = blockIdx.x * 4096;
    for (int i = tid; i < NBKT; i += 256) hist[i] = 0;
    __syncthreads();
#pragma unroll 4
    for (int j = 0; j < 16; ++j) {
        int e = base + j * 256 + tid;
        if (e < NNZE) atomicAdd(&hist[grows[e] >> 7], 1);
    }
    __syncthreads();
    for (int b = tid; b < NBKT; b += 256) {
        int n = hist[b];
        gcur[b] = n ? atomicAdd(&bcursor[b], n) : 0;
    }
    __syncthreads();
#pragma unroll 4
    for (int j = 0; j < 16; ++j) {
        int e = base + j * 256 + tid;
        if (e < NNZE) {
            int r = grows[e];
            int b = r >> 7;
            int pos = atomicAdd(&gcur[b], 1);
            temp[pos] = make_int2((gcols[e] & 0x1FFFF) | ((r & 127) << 17),
                                  __float_as_int(gvals[e]));
        }
    }
}

// ---------- Phase B: in-place within-bucket re-sort to CSR order ----------
__global__ __launch_bounds__(256) void binB(const int* __restrict__ rowptr,
                                            int* __restrict__ cursor,
                                            int2* __restrict__ sedge) {
    __shared__ int2 ebuf[BCAP];
    int b = blockIdx.x;
    int start = rowptr[b << 7];
    int end = rowptr[min((b + 1) << 7, NTOT)];
    int n = min(end - start, BCAP);
    for (int i = threadIdx.x; i < n; i += 256) ebuf[i] = sedge[start + i];
    __syncthreads();
    for (int i = threadIdx.x; i < n; i += 256) {
        int2 w = ebuf[i];
        int r = (b << 7) + ((w.x >> 17) & 127);
        int pos = atomicAdd(&cursor[r], 1);
        sedge[pos] = make_int2(w.x & 0x1FFFF, w.y);
    }
}

// ---------- SpMM layer (pull, scalar edge loads): one wave per row ----------
__global__ __launch_bounds__(256) void spmm16(const int* __restrict__ rowptr,
                                              const int2* __restrict__ sedge,
                                              const ushort_t* __restrict__ cur,
                                              ushort_t* __restrict__ nxt,
                                              float* __restrict__ sum_) {
    int row = __builtin_amdgcn_readfirstlane((blockIdx.x * 256 + threadIdx.x) >> 6);
    int lane = threadIdx.x & 63;
    if (row >= NTOT) return;
    int i = rowptr[row];
    int e = rowptr[row + 1];
    float acc = 0.f;
    for (; i + 4 <= e; i += 4) {
        int2 ed0 = sedge[i];
        int2 ed1 = sedge[i + 1];
        int2 ed2 = sedge[i + 2];
        int2 ed3 = sedge[i + 3];
        float x0 = bf2f(cur[(size_t)ed0.x * DD + lane]);
        float x1 = bf2f(cur[(size_t)ed1.x * DD + lane]);
        float x2 = bf2f(cur[(size_t)ed2.x * DD + lane]);
        float x3 = bf2f(cur[(size_t)ed3.x * DD + lane]);
        acc += __int_as_float(ed0.y) * x0;
        acc += __int_as_float(ed1.y) * x1;
        acc += __int_as_float(ed2.y) * x2;
        acc += __int_as_float(ed3.y) * x3;
    }
    for (; i < e; ++i) {
        int2 ed = sedge[i];
        acc += __int_as_float(ed.y) * bf2f(cur[(size_t)ed.x * DD + lane]);
    }
    size_t o = (size_t)row * DD + lane;
    nxt[o] = f2bf(acc);
    sum_[o] += acc;
}

// ---------- final gather + dot ----------
__global__ __launch_bounds__(256) void gamma_kernel(const int* __restrict__ users,
                                                    const int* __restrict__ items,
                                                    const float* __restrict__ sum_,
                                                    float* __restrict__ out) {
    int gid = blockIdx.x * 256 + threadIdx.x;
    int b = gid >> 6;
    int lane = gid & 63;
    if (b >= BBATCH) return;
    int u = users[b];
    int it = items[b];
    float pu = sum_[(size_t)u * DD + lane];
    float pi = sum_[(size_t)(NUM_USERS + it) * DD + lane];
    float p = pu * pi;
#pragma unroll
    for (int m = 32; m; m >>= 1) p += __shfl_xor(p, m);
    if (lane == 0) out[b] = p * 0.0625f;
}

extern "C" void kernel_launch(void* const* d_in, const int* in_sizes, int n_in,
                              void* d_out, int out_size, void* d_ws, size_t ws_size,
                              hipStream_t stream) {
    const int* users = (const int*)d_in[0];
    const int* items = (const int*)d_in[1];
    const int* adj = (const int*)d_in[2];
    const int* grows = (const int*)d_in[3];
    const int* gcols = (const int*)d_in[4];
    const float* gvals = (const float*)d_in[5];
    const float* sem = (const float*)d_in[6];
    const float* usem = (const float*)d_in[7];
    const float* emb_user = (const float*)d_in[8];
    const float* emb_item = (const float*)d_in[9];
    const float* W_sem = (const float*)d_in[10];
    const float* b_sem = (const float*)d_in[11];
    const float* W_usem = (const float*)d_in[12];
    const float* b_usem = (const float*)d_in[13];
    const float* W_att = (const float*)d_in[14];
    const float* a_att = (const float*)d_in[15];
    float* out = (float*)d_out;

    const size_t NE = (size_t)NTOT * DD;          // 5.76M
    const size_t IE = (size_t)NUM_ITEMS * DD;     // 1.92M
    char* p = (char*)d_ws;
    float* sum_ = (float*)p;        p += NE * 4;
    ushort_t* cur16 = (ushort_t*)p; p += NE * 2;
    ushort_t* nxt16 = (ushort_t*)p; p += NE * 2;
    float* M0 = (float*)p;          p += IE * 4;
    ushort_t* M0h = (ushort_t*)p;   p += IE * 2;
    int2* sedge = (int2*)p;         p += (size_t)NNZE * 8;
    ushort_t* WThiU = (ushort_t*)p; p += 65536 * 2;
    ushort_t* WTloU = (ushort_t*)p; p += 65536 * 2;
    ushort_t* WThiS = (ushort_t*)p; p += 65536 * 2;
    ushort_t* WTloS = (ushort_t*)p; p += 65536 * 2;
    float* s1 = (float*)p;          p += NUM_ITEMS * 4;
    float* s2 = (float*)p;          p += NUM_ITEMS * 4;
    float* wa1 = (float*)p;         p += SEMD * 4;
    float* wa2 = (float*)p;         p += SEMD * 4;
    int* cnt = (int*)p;             p += NTOT * 4;
    int* rowptr = (int*)p;          p += (NTOT + 4) * 4;
    int* cursor = (int*)p;          p += NTOT * 4;
    int* bsum = (int*)p;            p += 96 * 4;
    int* boff = (int*)p;            p += 96 * 4;
    int* bcursor = (int*)p;         p += NBKT * 4;

    wsplit<<<513, 256, 0, stream>>>(W_usem, W_sem, WThiU, WTloU, WThiS, WTloS,
                                    W_att, a_att, wa1, wa2);

    gemm_mfma<false><<<(NUM_USERS + 63) / 64, 256, 0, stream>>>(
        usem, WThiU, WTloU, b_usem, emb_user, sum_, cur16, NUM_USERS,
        nullptr, nullptr, nullptr, nullptr);
    gemm_mfma<true><<<(NUM_ITEMS + 63) / 64, 256, 0, stream>>>(
        sem, WThiS, WTloS, b_sem, emb_item, M0, M0h, NUM_ITEMS,
        wa1, wa2, s1, s2);

    att_kernel<<<(NUM_ITEMS * 64 + 255) / 256, 256, 0, stream>>>(adj, s1, s2, M0, M0h,
                                                                 cur16, sum_);

    hipMemsetAsync(cnt, 0, NTOT * sizeof(int), stream);
    hist_kernel<<<(NNZE + 255) / 256, 256, 0, stream>>>(grows, cnt);
    scan_blocksums<<<SCAN_NB, 256, 0, stream>>>(cnt, bsum);
    scan_bsums<<<1, 128, 0, stream>>>(bsum, boff, rowptr);
    scan_write<<<SCAN_NB, 256, 0, stream>>>(cnt, boff, rowptr, cursor, bcursor);
    binA<<<(NNZE + 4095) / 4096, 256, 0, stream>>>(grows, gcols, gvals, bcursor, sedge);
    binB<<<NBKT, 256, 0, stream>>>(rowptr, cursor, sedge);

    ushort_t* cur = cur16;
    ushort_t* nxt = nxt16;
    for (int l = 0; l < NLAYERS; ++l) {
        spmm16<<<(NTOT * 64 + 255) / 256, 256, 0, stream>>>(rowptr, sedge, cur, nxt, sum_);
        ushort_t* t = cur;
        cur = nxt;
        nxt = t;
    }
    gamma_kernel<<<(BBATCH * 64 + 255) / 256, 256, 0, stream>>>(users, items, sum_, out);
}